// Round 11
// baseline (227.312 us; speedup 1.0000x reference)
//
#include <hip/hip_runtime.h>
#include <math.h>

#define N_TOK 4096
#define D_DIM 512
#define M_EXP 512
#define B_DIM 8
#define K_TOP 16
#define MB    4096          // M_EXP * B_DIM
#define UROW  4104          // (D_DIM+1) * B_DIM
#define EPSV  1e-8f
#define KTOT  1536          // 3 * D (split-bf16 K blocks for GEMM1)

typedef unsigned short ushort8 __attribute__((ext_vector_type(8)));
typedef unsigned short ushort4v __attribute__((ext_vector_type(4)));
typedef short short8 __attribute__((ext_vector_type(8)));
typedef float f32x16 __attribute__((ext_vector_type(16)));

__device__ inline float b2f(unsigned short u) {
    union { unsigned int i; float f; } c;
    c.i = ((unsigned int)u) << 16;
    return c.f;
}
__device__ inline unsigned short f2b(float f) {     // RNE bf16
    union { float f; unsigned int i; } c; c.f = f;
    unsigned int lsb = (c.i >> 16) & 1;
    c.i += 0x7fffu + lsb;
    return (unsigned short)(c.i >> 16);
}
__device__ inline void gload_lds16(const unsigned short* g, unsigned short* l) {
    __builtin_amdgcn_global_load_lds(
        (const __attribute__((address_space(1))) unsigned int*)g,
        (__attribute__((address_space(3))) unsigned int*)l, 16, 0, 0);
}

// --- merged: blocks 0-1023 normalize x rows (+Abf); 1024-1535 V/U norm partials ---
__global__ __launch_bounds__(256) void k_norm_x_part(const float* __restrict__ x,
                                                     float* __restrict__ xn,
                                                     unsigned short* __restrict__ Abf,
                                                     int* __restrict__ counts,
                                                     const float* __restrict__ V,
                                                     const float* __restrict__ U,
                                                     float* __restrict__ partV,
                                                     float* __restrict__ partU)
{
    int blk = blockIdx.x;
    if (blk < 1024) {
        if (blk == 0) {
            counts[threadIdx.x] = 0;
            counts[threadIdx.x + 256] = 0;
        }
        int wave = threadIdx.x >> 6;
        int lane = threadIdx.x & 63;
        int n = blk * 4 + wave;
        const float4* xp = (const float4*)&x[(size_t)n * D_DIM + lane * 8];
        float4 a = xp[0], b = xp[1];
        float s = a.x*a.x + a.y*a.y + a.z*a.z + a.w*a.w
                + b.x*b.x + b.y*b.y + b.z*b.z + b.w*b.w;
        #pragma unroll
        for (int off = 1; off < 64; off <<= 1) s += __shfl_xor(s, off);
        float inv = 1.0f / fmaxf(sqrtf(s), EPSV);
        float v[8] = {a.x*inv, a.y*inv, a.z*inv, a.w*inv,
                      b.x*inv, b.y*inv, b.z*inv, b.w*inv};
        float4* op = (float4*)&xn[(size_t)n * D_DIM + lane * 8];
        op[0] = make_float4(v[0], v[1], v[2], v[3]);
        op[1] = make_float4(v[4], v[5], v[6], v[7]);
        ushort8 hi, lo;
        #pragma unroll
        for (int j = 0; j < 8; ++j) {
            unsigned short h = f2b(v[j]);
            hi[j] = h;
            lo[j] = f2b(v[j] - b2f(h));
        }
        size_t base = (size_t)n * KTOT + lane * 8;
        *(ushort8*)&Abf[base]        = hi;
        *(ushort8*)&Abf[base + 512]  = hi;
        *(ushort8*)&Abf[base + 1024] = lo;
    } else if (blk < 1280) {
        blk -= 1024;
        int s = blk >> 4;
        int t = (blk & 15) * 256 + threadIdx.x;
        float sum = 0.f;
        int d0 = s * 32;
        #pragma unroll 8
        for (int d = d0; d < d0 + 32; ++d) {
            float v = V[(size_t)d * MB + t];
            sum += v * v;
        }
        partV[(size_t)s * MB + t] = sum;
    } else {
        blk -= 1280;
        int s = blk >> 4;
        int t = (blk & 15) * 256 + threadIdx.x;
        int m = t >> 3, b = t & 7;
        size_t base = (size_t)m * UROW + b;
        int pbeg = s * 32;
        int pend = (s == 15) ? 513 : pbeg + 32;
        float sum = 0.f;
        for (int p = pbeg; p < pend; ++p) {
            float u = U[base + (size_t)p * 8];
            sum += u * u;
        }
        partU[(size_t)s * MB + t] = sum;
    }
}

// ---- merged normalize+emit: blocks 0-255 -> V path, 256-511 -> U path ----
__global__ __launch_bounds__(256) void k_norm_UV2(const float* __restrict__ V,
                                                  const float* __restrict__ U,
                                                  const float* __restrict__ partV,
                                                  const float* __restrict__ partU,
                                                  unsigned short* __restrict__ Btbf,
                                                  unsigned short* __restrict__ WXt,
                                                  unsigned short* __restrict__ U2t)
{
    int blk = blockIdx.x;
    if (blk < 256) {
        int s = blk >> 4;
        int t = (blk & 15) * 256 + threadIdx.x;
        float n2 = 0.f;
        #pragma unroll
        for (int i = 0; i < 16; ++i) n2 += partV[(size_t)i * MB + t];
        float inv = 1.0f / fmaxf(sqrtf(n2), EPSV);
        size_t row = (size_t)t * KTOT;
        int dbeg = s * 32;
        for (int d0 = dbeg; d0 < dbeg + 32; d0 += 8) {
            ushort8 hi, lo;
            #pragma unroll
            for (int j = 0; j < 8; ++j) {
                float f = V[(size_t)(d0 + j) * MB + t] * inv;
                unsigned short h = f2b(f);
                hi[j] = h;
                lo[j] = f2b(f - b2f(h));
                WXt[(size_t)(512 + d0 + j) * MB + t] = h;
            }
            *(ushort8*)&Btbf[row + d0]        = hi;
            *(ushort8*)&Btbf[row + 512 + d0]  = lo;
            *(ushort8*)&Btbf[row + 1024 + d0] = hi;
        }
    } else {
        blk -= 256;
        int s = blk >> 4;
        int t = (blk & 15) * 256 + threadIdx.x;
        int m = t >> 3, b = t & 7;
        size_t base = (size_t)m * UROW + b;
        float n2 = 0.f;
        #pragma unroll
        for (int i = 0; i < 16; ++i) n2 += partU[(size_t)i * MB + t];
        float inv = 1.0f / fmaxf(sqrtf(n2), EPSV);
        int pbeg = s * 32;
        for (int p0 = pbeg; p0 < pbeg + 32; p0 += 8) {
            ushort8 h8;
            #pragma unroll
            for (int j = 0; j < 8; ++j) {
                unsigned short h = f2b(U[base + (size_t)(p0 + j) * 8] * inv);
                h8[j] = h;
                WXt[(size_t)(p0 + j) * MB + t] = h;
            }
            *(ushort8*)&U2t[(size_t)t * D_DIM + p0] = h8;
        }
    }
}

// ============ 8-phase 256x256 bf16 GEMM, 32x32x16 MFMA (T3+T4+T5, k-slot swizzle) ============
// A row-major (4096 x KROW), Bt col-major (Bt[col*KROW + k]).
// LDS: lds[buf][op][kc][row*32 + k], unit (buf,op,kc) = 16KB staged by 2 gload_lds16/thread.
// k-slot swizzle f(r)=(r>>1)&3: physical slot p of row r holds logical slot p ^ f(r);
// read undoes it: slot = (logical) ^ f(row). Both-sides consistent (rule #21).
// 32x32x16 operand: row/col = lane&31, k-group = lane>>5 (logical slot = ks*2 + (lane>>5)).
// Phase MH=0: m-tiles 0,1 + B reads (8 ds_reads); MH=1: m-tiles 2,3 (4 ds_reads).
template<int KROW, int BUF, int KC, int MH, bool READB, int SBUF, int SOP, int SKC, bool DOVM>
__device__ __forceinline__ void gemm_phase(const unsigned short* __restrict__ A,
                                           const unsigned short* __restrict__ Bt,
                                           unsigned short (*lds)[2][2][8192],
                                           f32x16 (&acc)[4][2], short8 (&bfr)[2][2],
                                           int wr, int wc, int lane, int wid,
                                           int brow, int bcol, int stile)
{
    const unsigned short* aun = lds[BUF][0][KC];
    const unsigned short* bun = lds[BUF][1][KC];
    int l5 = lane >> 5;
    int r31 = lane & 31;
    short8 af[2][2];
    #pragma unroll
    for (int mi = 0; mi < 2; ++mi) {
        int rowL = wr * 128 + (MH * 2 + mi) * 32 + r31;
        #pragma unroll
        for (int ks = 0; ks < 2; ++ks) {
            int slot = (ks * 2 + l5) ^ ((rowL >> 1) & 3);
            af[mi][ks] = *(const short8*)&aun[rowL * 32 + slot * 8];
        }
    }
    if (READB) {
        #pragma unroll
        for (int ni = 0; ni < 2; ++ni) {
            int colL = wc * 64 + ni * 32 + r31;
            #pragma unroll
            for (int ks = 0; ks < 2; ++ks) {
                int slot = (ks * 2 + l5) ^ ((colL >> 1) & 3);
                bfr[ni][ks] = *(const short8*)&bun[colL * 32 + slot * 8];
            }
        }
    }
    // stage one unit (pre-swizzled global source, linear LDS dest)
    {
        const unsigned short* src = SOP ? Bt : A;
        int rbase = SOP ? bcol : brow;
        #pragma unroll
        for (int j = 0; j < 2; ++j) {
            int c = wid * 128 + j * 64 + lane;
            int row = c >> 2, k8 = c & 3;
            int k8s = k8 ^ ((row >> 1) & 3);
            const unsigned short* gp = src + (size_t)(rbase + row) * KROW
                                     + stile * 64 + SKC * 32 + k8s * 8;
            unsigned short* lp = lds[SBUF][SOP][SKC] + (wid * 128 + j * 64) * 8;
            gload_lds16(gp, lp);
        }
    }
    __builtin_amdgcn_sched_barrier(0);
    __builtin_amdgcn_s_barrier();
    asm volatile("s_waitcnt lgkmcnt(0)" ::: "memory");
    __builtin_amdgcn_sched_barrier(0);
    __builtin_amdgcn_s_setprio(1);
    #pragma unroll
    for (int mi = 0; mi < 2; ++mi)
        #pragma unroll
        for (int ni = 0; ni < 2; ++ni)
            #pragma unroll
            for (int ks = 0; ks < 2; ++ks)
                acc[MH * 2 + mi][ni] = __builtin_amdgcn_mfma_f32_32x32x16_bf16(
                    af[mi][ks], bfr[ni][ks], acc[MH * 2 + mi][ni], 0, 0, 0);
    __builtin_amdgcn_s_setprio(0);
    if (DOVM) asm volatile("s_waitcnt vmcnt(8)" ::: "memory");
    __builtin_amdgcn_sched_barrier(0);
    __builtin_amdgcn_s_barrier();
    __builtin_amdgcn_sched_barrier(0);
}

// KROW: row stride of A and Bt; KLEN: K extent per wg (split-K slice); NCOLT: output
// 256-col tiles; SPLITK: slices (partial slabs of 4096*LDC fp32 each, concatenated).
// OUTMODE 0: C fp32.  2: Cb bf16.  3: Cb = h bf16 (ld 4096) + C = energy fp32 (ld 512).
// OUTMODE 4: writer-loss fused: Cb = hbf INPUT (masked h, ld 4096); C[bid] = block partial.
// C/D layout (32x32x16): col=lane&31, row=(reg&3)+8*(reg>>2)+4*(lane>>5)  [m74/m101]
template<int KROW, int KLEN, int NCOLT, int SPLITK, int LDC, int OUTMODE>
__global__ __launch_bounds__(512, 1) void k_gemm8(const unsigned short* __restrict__ A,
                                                  const unsigned short* __restrict__ Bt,
                                                  float* __restrict__ C,
                                                  unsigned short* __restrict__ Cb)
{
    __shared__ unsigned short lds[2][2][2][8192];   // 128 KiB

    constexpr int KT   = KLEN / 64;
    constexpr int NIT  = KLEN / 128;
    constexpr int ROWT = 16;                        // 4096 / 256
    constexpr int NWG  = ROWT * NCOLT * SPLITK;     // must be % 8 == 0

    int tid = threadIdx.x;
    int wid = tid >> 6;
    int lane = tid & 63;
    int wr = wid >> 2, wc = wid & 3;
    int l5 = lane >> 5;
    int r31 = lane & 31;

    int bid = blockIdx.x;
    int swz = (bid & 7) * (NWG / 8) + (bid >> 3);
    int ks   = swz / (ROWT * NCOLT);
    int tile = swz % (ROWT * NCOLT);
    int brow = (tile / NCOLT) * 256;
    int bcol = (tile % NCOLT) * 256;

    const unsigned short* Aofs = A + (size_t)ks * KLEN;
    const unsigned short* Bofs = Bt + (size_t)ks * KLEN;
    float* Cofs = C + (size_t)ks * 4096 * LDC;

    f32x16 acc[4][2] = {};
    short8 bfr[2][2];

    // ---- prologue: stage tile0 (4 units) + tile1.kc0 (2 units) ----
    auto stage0 = [&](int sbuf, int sop, int skc, int stile) {
        const unsigned short* src = sop ? Bofs : Aofs;
        int rbase = sop ? bcol : brow;
        #pragma unroll
        for (int j = 0; j < 2; ++j) {
            int c = wid * 128 + j * 64 + lane;
            int row = c >> 2, k8 = c & 3;
            int k8s = k8 ^ ((row >> 1) & 3);
            const unsigned short* gp = src + (size_t)(rbase + row) * KROW
                                     + stile * 64 + skc * 32 + k8s * 8;
            unsigned short* lp = lds[sbuf][sop][skc] + (wid * 128 + j * 64) * 8;
            gload_lds16(gp, lp);
        }
    };
    stage0(0, 0, 0, 0); stage0(0, 1, 0, 0);
    stage0(0, 0, 1, 0); stage0(0, 1, 1, 0);
    stage0(1, 0, 0, 1); stage0(1, 1, 0, 1);
    asm volatile("s_waitcnt vmcnt(8)" ::: "memory");
    __builtin_amdgcn_sched_barrier(0);
    __builtin_amdgcn_s_barrier();
    __builtin_amdgcn_sched_barrier(0);

    for (int i = 0; i < NIT; ++i) {
        int t1 = 2 * i + 1; if (t1 > KT - 1) t1 = KT - 1;
        int t2 = 2 * i + 2; if (t2 > KT - 1) t2 = KT - 1;
        int t3 = 2 * i + 3; if (t3 > KT - 1) t3 = KT - 1;
        gemm_phase<KROW, 0, 0, 0, true , 1, 0, 1, false>(Aofs, Bofs, lds, acc, bfr, wr, wc, lane, wid, brow, bcol, t1);
        gemm_phase<KROW, 0, 0, 1, false, 1, 1, 1, true >(Aofs, Bofs, lds, acc, bfr, wr, wc, lane, wid, brow, bcol, t1);
        gemm_phase<KROW, 0, 1, 0, true , 0, 0, 0, false>(Aofs, Bofs, lds, acc, bfr, wr, wc, lane, wid, brow, bcol, t2);
        gemm_phase<KROW, 0, 1, 1, false, 0, 1, 0, true >(Aofs, Bofs, lds, acc, bfr, wr, wc, lane, wid, brow, bcol, t2);
        gemm_phase<KROW, 1, 0, 0, true , 0, 0, 1, false>(Aofs, Bofs, lds, acc, bfr, wr, wc, lane, wid, brow, bcol, t2);
        gemm_phase<KROW, 1, 0, 1, false, 0, 1, 1, true >(Aofs, Bofs, lds, acc, bfr, wr, wc, lane, wid, brow, bcol, t2);
        gemm_phase<KROW, 1, 1, 0, true , 1, 0, 0, false>(Aofs, Bofs, lds, acc, bfr, wr, wc, lane, wid, brow, bcol, t3);
        gemm_phase<KROW, 1, 1, 1, false, 1, 1, 0, true >(Aofs, Bofs, lds, acc, bfr, wr, wc, lane, wid, brow, bcol, t3);
    }

    // epilogue
    if (OUTMODE == 0 || OUTMODE == 2) {
        #pragma unroll
        for (int mt = 0; mt < 4; ++mt) {
            #pragma unroll
            for (int nt = 0; nt < 2; ++nt) {
                int col = bcol + wc * 64 + nt * 32 + r31;
                #pragma unroll
                for (int r = 0; r < 16; ++r) {
                    int row = brow + wr * 128 + mt * 32 + (r & 3) + 8 * (r >> 2) + 4 * l5;
                    if (OUTMODE == 0)
                        Cofs[(size_t)row * LDC + col] = acc[mt][nt][r];
                    else
                        Cb[(size_t)row * LDC + col] = f2b(acc[mt][nt][r]);
                }
            }
        }
    } else if (OUTMODE == 3) {
        #pragma unroll
        for (int mt = 0; mt < 4; ++mt) {
            #pragma unroll
            for (int nt = 0; nt < 2; ++nt) {
                int col = bcol + wc * 64 + nt * 32 + r31;
                #pragma unroll
                for (int r = 0; r < 16; ++r) {
                    int row = brow + wr * 128 + mt * 32 + (r & 3) + 8 * (r >> 2) + 4 * l5;
                    float a = acc[mt][nt][r];
                    Cb[(size_t)row * 4096 + col] = f2b(a);
                    // energy: sum h^2 over the 8-lane col-group (3x shfl_xor tree)
                    float sq = a * a;
                    sq += __shfl_xor(sq, 1);
                    sq += __shfl_xor(sq, 2);
                    sq += __shfl_xor(sq, 4);
                    if ((lane & 7) == 0) {
                        int e = (bcol + wc * 64 + nt * 32 + r31) >> 3;
                        C[(size_t)row * 512 + e] = sq;
                    }
                }
            }
        }
    } else {  // OUTMODE 4: writer loss partial, no hrecon materialization
        float local = 0.f;
        #pragma unroll
        for (int mt = 0; mt < 4; ++mt) {
            #pragma unroll
            for (int nt = 0; nt < 2; ++nt) {
                int col = bcol + wc * 64 + nt * 32 + r31;
                #pragma unroll
                for (int r = 0; r < 16; ++r) {
                    int row = brow + wr * 128 + mt * 32 + (r & 3) + 8 * (r >> 2) + 4 * l5;
                    unsigned short hbits = Cb[(size_t)row * 4096 + col];
                    if (hbits & 0x7fffu) {
                        float d = acc[mt][nt][r] - b2f(hbits);
                        local += d * d;
                    }
                }
            }
        }
        __syncthreads();                 // LDS dead after K-loop; reuse for reduction
        float* red = (float*)lds;
        red[tid] = local;
        __syncthreads();
        for (int s = 256; s > 0; s >>= 1) {
            if (tid < s) red[tid] += red[tid + s];
            __syncthreads();
        }
        if (tid == 0) C[bid] = red[0];
    }
}

// ---- top-16 from energy; mask hbf in place (one wave per token) ----
__global__ __launch_bounds__(256) void k_topk2(const float* __restrict__ energy,
                                               unsigned short* __restrict__ hbf,
                                               int* __restrict__ topk_idx,
                                               int* __restrict__ counts)
{
    int wave = threadIdx.x >> 6;
    int lane = threadIdx.x & 63;
    int n = blockIdx.x * 4 + wave;
    float ev[8];
    #pragma unroll
    for (int i = 0; i < 8; ++i) ev[i] = energy[(size_t)n * M_EXP + i * 64 + lane];
    for (int r = 0; r < K_TOP; ++r) {
        float bv = -1.0f; int bi = 0;
        #pragma unroll
        for (int i = 0; i < 8; ++i) {
            if (ev[i] > bv) { bv = ev[i]; bi = i * 64 + lane; }
        }
        #pragma unroll
        for (int off = 1; off < 64; off <<= 1) {
            float ov = __shfl_xor(bv, off);
            int   oi = __shfl_xor(bi, off);
            if (ov > bv || (ov == bv && oi < bi)) { bv = ov; bi = oi; }
        }
        if (lane == 0) {
            topk_idx[n * K_TOP + r] = bi;
            atomicAdd(&counts[bi], 1);
        }
        #pragma unroll
        for (int i = 0; i < 8; ++i)
            if (((bi >> 6) == i) && (lane == (bi & 63))) ev[i] = -INFINITY;
    }
    // zero non-selected experts' h (selected entries already hold h from GEMM1)
    ushort8 z = {0, 0, 0, 0, 0, 0, 0, 0};
    #pragma unroll
    for (int i = 0; i < 8; ++i) {
        int e = i * 64 + lane;
        if (ev[i] != -INFINITY)
            *(ushort8*)&hbf[(size_t)n * MB + e * 8] = z;
    }
}

// ---- fused: reduce 4 split-K partials + x_out + uncap + writesb (one token/block) ----
__global__ __launch_bounds__(256) void k_reduce_fin(const float* __restrict__ P,
                                                    const float* __restrict__ xn,
                                                    float* __restrict__ x_out,
                                                    unsigned short* __restrict__ wb,
                                                    float* __restrict__ uncap)
{
    const size_t S = (size_t)4096 * 1024;
    int n = blockIdx.x;
    int t = threadIdx.x;
    int c = t * 4;                               // 0..1023, step 4
    size_t base = (size_t)n * 1024 + c;
    float4 a = *(const float4*)&P[base];
    float4 b = *(const float4*)&P[base + S];
    float4 cc = *(const float4*)&P[base + 2 * S];
    float4 d = *(const float4*)&P[base + 3 * S];
    float4 v = make_float4(a.x + b.x + cc.x + d.x, a.y + b.y + cc.y + d.y,
                           a.z + b.z + cc.z + d.z, a.w + b.w + cc.w + d.w);
    bool isW = (c < 512);
    int xc = isW ? c : (c - 512);
    float4 xv = *(const float4*)&xn[(size_t)n * D_DIM + xc];
    float4 yr;                                    // y (writes half) or resid (xhat half)
    if (isW) yr = make_float4(xv.x + v.x, xv.y + v.y, xv.z + v.z, xv.w + v.w);
    else     yr = make_float4(xv.x - v.x, xv.y - v.y, xv.z - v.z, xv.w - v.w);
    float local = yr.x*yr.x + yr.y*yr.y + yr.z*yr.z + yr.w*yr.w;

    __shared__ float red[256];
    __shared__ float sinv;
    red[t] = local;
    __syncthreads();
    for (int s = 64; s > 0; s >>= 1) {
        if ((t & 127) < s) red[t] += red[t + s];
        __syncthreads();
    }
    if (t == 0) {
        uncap[n] = red[128];                      // sum resid^2
        sinv = 1.0f / fmaxf(sqrtf(red[0]), EPSV); // from sum y^2
    }
    __syncthreads();
    if (isW) {
        float inv = sinv;
        *(float4*)&x_out[(size_t)n * D_DIM + c] =
            make_float4(yr.x*inv, yr.y*inv, yr.z*inv, yr.w*inv);
        ushort4v o;
        o[0] = f2b(yr.x); o[1] = f2b(yr.y); o[2] = f2b(yr.z); o[3] = f2b(yr.w);
        *(ushort4v*)&wb[(size_t)n * 512 + c] = o;
    }
}

// ---------------- final scalar reductions + counts ----------------
__global__ __launch_bounds__(256) void k_finalize(const float* __restrict__ uncap,
                                                  const float* __restrict__ writer_part,
                                                  const int* __restrict__ counts,
                                                  float* __restrict__ out)
{
    __shared__ float ru[256], rw[256];
    int t = threadIdx.x;
    float su = 0.f;
    for (int i = t; i < N_TOK; i += 256) su += uncap[i];
    float sw = writer_part[t];                    // exactly 256 partials
    ru[t] = su; rw[t] = sw;
    __syncthreads();
    for (int s = 128; s > 0; s >>= 1) {
        if (t < s) { ru[t] += ru[t + s]; rw[t] += rw[t + s]; }
        __syncthreads();
    }
    if (t == 0)
        out[(size_t)N_TOK * D_DIM] = ru[0] / (float)N_TOK
                                   + rw[0] / (float)(N_TOK * K_TOP * B_DIM);
    for (int i = t; i < M_EXP; i += 256)
        out[(size_t)N_TOK * D_DIM + 1 + i] = (float)counts[i];
}

extern "C" void kernel_launch(void* const* d_in, const int* in_sizes, int n_in,
                              void* d_out, int out_size, void* d_ws, size_t ws_size,
                              hipStream_t stream)
{
    const float* x = (const float*)d_in[0];
    const float* V = (const float*)d_in[1];
    const float* U = (const float*)d_in[2];
    float* out = (float*)d_out;

    float* ws     = (float*)d_ws;
    float* xn     = ws;                        // 2,097,152 f  (8.4 MB)
    float* P      = xn + 2097152;              // 16,777,216 f (67.1 MB): GEMM1 energy,
                                               //   then GEMM23 split-K partials
    float* uncap  = P + 16777216;              // 4096 f
    float* writer_part = uncap + 4096;         // 256 f (+pad)
    int*   topk_i = (int*)(writer_part + 512); // 65,536 i
    int*   counts = topk_i + 65536;            // 512 i (+pad)
    float* partV  = (float*)(counts + 1024);   // 65,536 f
    float* partU  = partV + 65536;             // 65,536 f
    unsigned short* hbf = (unsigned short*)(partU + 65536);  // 16,777,216 us (33.6 MB)
    unsigned short* U2t = hbf + 16777216;      // 2,097,152 us (4.2 MB)
    unsigned short* WXt = U2t + 2097152;       // 4,194,304 us (8.4 MB)
    unsigned short* R   = WXt + 4194304;       // 12,582,912 us (25.2 MB)
    unsigned short* Abf  = R;                  // 6,291,456 us (gemm1 A')
    unsigned short* Btbf = R + 6291456;        // 6,291,456 us (gemm1 B')
    unsigned short* writesb = R;               // 2,097,152 us (aliases Abf after GEMM1)
    float* energy = P;                         // 2,097,152 f ⊂ P
    // total ws use ~148 MB

    k_norm_x_part<<<1536, 256, 0, stream>>>(x, xn, Abf, counts, V, U, partV, partU);
    k_norm_UV2  <<<512, 256, 0, stream>>>(V, U, partV, partU, Btbf, WXt, U2t);
    // GEMM1: h = A'(4096x1536) @ B'(1536x4096) -> hbf bf16 + energy fp32 (epilogue-fused)
    k_gemm8<KTOT, KTOT, 16, 1, 4096, 3><<<256, 512, 0, stream>>>(Abf, Btbf, energy, hbf);
    k_topk2     <<<N_TOK / 4, 256, 0, stream>>>(energy, hbf, topk_i, counts);
    // GEMM23: partial[ks] = hbf(4096x4096, K-slice ks) @ WXt^T -> 4x(4096x1024) in P
    k_gemm8<4096, 1024, 4, 4, 1024, 0><<<256, 512, 0, stream>>>(hbf, WXt, P, nullptr);
    // fused reduce + x_out + uncap + writes bf16
    k_reduce_fin<<<4096, 256, 0, stream>>>(P, xn, out, writesb, uncap);
    // GEMM4 fused writer-loss: hrecon tile vs hbf, per-block partials (no hrecon write)
    k_gemm8<D_DIM, D_DIM, 16, 1, 4096, 4><<<256, 512, 0, stream>>>(writesb, U2t, writer_part, hbf);
    k_finalize  <<<1, 256, 0, stream>>>(uncap, writer_part, counts, out);
}

// Round 12
// 212.979 us; speedup vs baseline: 1.0673x; 1.0673x over previous
//
#include <hip/hip_runtime.h>
#include <math.h>

#define N_TOK 4096
#define D_DIM 512
#define M_EXP 512
#define B_DIM 8
#define K_TOP 16
#define MB    4096          // M_EXP * B_DIM
#define UROW  4104          // (D_DIM+1) * B_DIM
#define EPSV  1e-8f
#define KTOT  1536          // 3 * D (split-bf16 K blocks for GEMM1)

typedef unsigned short ushort8 __attribute__((ext_vector_type(8)));
typedef unsigned short ushort4v __attribute__((ext_vector_type(4)));
typedef short short8 __attribute__((ext_vector_type(8)));
typedef float f32x4 __attribute__((ext_vector_type(4)));

__device__ inline float b2f(unsigned short u) {
    union { unsigned int i; float f; } c;
    c.i = ((unsigned int)u) << 16;
    return c.f;
}
__device__ inline unsigned short f2b(float f) {     // RNE bf16
    union { float f; unsigned int i; } c; c.f = f;
    unsigned int lsb = (c.i >> 16) & 1;
    c.i += 0x7fffu + lsb;
    return (unsigned short)(c.i >> 16);
}
__device__ inline void gload_lds16(const unsigned short* g, unsigned short* l) {
    __builtin_amdgcn_global_load_lds(
        (const __attribute__((address_space(1))) unsigned int*)g,
        (__attribute__((address_space(3))) unsigned int*)l, 16, 0, 0);
}

// --- merged: blocks 0-1023 normalize x rows (+Abf); 1024-1535 V/U norm partials ---
__global__ __launch_bounds__(256) void k_norm_x_part(const float* __restrict__ x,
                                                     float* __restrict__ xn,
                                                     unsigned short* __restrict__ Abf,
                                                     int* __restrict__ counts,
                                                     const float* __restrict__ V,
                                                     const float* __restrict__ U,
                                                     float* __restrict__ partV,
                                                     float* __restrict__ partU)
{
    int blk = blockIdx.x;
    if (blk < 1024) {
        if (blk == 0) {
            counts[threadIdx.x] = 0;
            counts[threadIdx.x + 256] = 0;
        }
        int wave = threadIdx.x >> 6;
        int lane = threadIdx.x & 63;
        int n = blk * 4 + wave;
        const float4* xp = (const float4*)&x[(size_t)n * D_DIM + lane * 8];
        float4 a = xp[0], b = xp[1];
        float s = a.x*a.x + a.y*a.y + a.z*a.z + a.w*a.w
                + b.x*b.x + b.y*b.y + b.z*b.z + b.w*b.w;
        #pragma unroll
        for (int off = 1; off < 64; off <<= 1) s += __shfl_xor(s, off);
        float inv = 1.0f / fmaxf(sqrtf(s), EPSV);
        float v[8] = {a.x*inv, a.y*inv, a.z*inv, a.w*inv,
                      b.x*inv, b.y*inv, b.z*inv, b.w*inv};
        float4* op = (float4*)&xn[(size_t)n * D_DIM + lane * 8];
        op[0] = make_float4(v[0], v[1], v[2], v[3]);
        op[1] = make_float4(v[4], v[5], v[6], v[7]);
        ushort8 hi, lo;
        #pragma unroll
        for (int j = 0; j < 8; ++j) {
            unsigned short h = f2b(v[j]);
            hi[j] = h;
            lo[j] = f2b(v[j] - b2f(h));
        }
        size_t base = (size_t)n * KTOT + lane * 8;
        *(ushort8*)&Abf[base]        = hi;
        *(ushort8*)&Abf[base + 512]  = hi;
        *(ushort8*)&Abf[base + 1024] = lo;
    } else if (blk < 1280) {
        blk -= 1024;
        int s = blk >> 4;
        int t = (blk & 15) * 256 + threadIdx.x;
        float sum = 0.f;
        int d0 = s * 32;
        #pragma unroll 8
        for (int d = d0; d < d0 + 32; ++d) {
            float v = V[(size_t)d * MB + t];
            sum += v * v;
        }
        partV[(size_t)s * MB + t] = sum;
    } else {
        blk -= 1280;
        int s = blk >> 4;
        int t = (blk & 15) * 256 + threadIdx.x;
        int m = t >> 3, b = t & 7;
        size_t base = (size_t)m * UROW + b;
        int pbeg = s * 32;
        int pend = (s == 15) ? 513 : pbeg + 32;
        float sum = 0.f;
        for (int p = pbeg; p < pend; ++p) {
            float u = U[base + (size_t)p * 8];
            sum += u * u;
        }
        partU[(size_t)s * MB + t] = sum;
    }
}

// ---- merged normalize+emit: blocks 0-255 -> V path, 256-511 -> U path ----
__global__ __launch_bounds__(256) void k_norm_UV2(const float* __restrict__ V,
                                                  const float* __restrict__ U,
                                                  const float* __restrict__ partV,
                                                  const float* __restrict__ partU,
                                                  unsigned short* __restrict__ Btbf,
                                                  unsigned short* __restrict__ WXt,
                                                  unsigned short* __restrict__ U2t)
{
    int blk = blockIdx.x;
    if (blk < 256) {
        int s = blk >> 4;
        int t = (blk & 15) * 256 + threadIdx.x;
        float n2 = 0.f;
        #pragma unroll
        for (int i = 0; i < 16; ++i) n2 += partV[(size_t)i * MB + t];
        float inv = 1.0f / fmaxf(sqrtf(n2), EPSV);
        size_t row = (size_t)t * KTOT;
        int dbeg = s * 32;
        for (int d0 = dbeg; d0 < dbeg + 32; d0 += 8) {
            ushort8 hi, lo;
            #pragma unroll
            for (int j = 0; j < 8; ++j) {
                float f = V[(size_t)(d0 + j) * MB + t] * inv;
                unsigned short h = f2b(f);
                hi[j] = h;
                lo[j] = f2b(f - b2f(h));
                WXt[(size_t)(512 + d0 + j) * MB + t] = h;
            }
            *(ushort8*)&Btbf[row + d0]        = hi;
            *(ushort8*)&Btbf[row + 512 + d0]  = lo;
            *(ushort8*)&Btbf[row + 1024 + d0] = hi;
        }
    } else {
        blk -= 256;
        int s = blk >> 4;
        int t = (blk & 15) * 256 + threadIdx.x;
        int m = t >> 3, b = t & 7;
        size_t base = (size_t)m * UROW + b;
        float n2 = 0.f;
        #pragma unroll
        for (int i = 0; i < 16; ++i) n2 += partU[(size_t)i * MB + t];
        float inv = 1.0f / fmaxf(sqrtf(n2), EPSV);
        int pbeg = s * 32;
        for (int p0 = pbeg; p0 < pbeg + 32; p0 += 8) {
            ushort8 h8;
            #pragma unroll
            for (int j = 0; j < 8; ++j) {
                unsigned short h = f2b(U[base + (size_t)(p0 + j) * 8] * inv);
                h8[j] = h;
                WXt[(size_t)(p0 + j) * MB + t] = h;
            }
            *(ushort8*)&U2t[(size_t)t * D_DIM + p0] = h8;
        }
    }
}

// ================== 8-phase 256x256 bf16 GEMM (T3+T4+T5, k-slot swizzle) ==================
// A row-major (4096 x KROW), Bt col-major (Bt[col*KROW + k]).
// LDS: lds[buf][op][kc][row*32 + k], unit (buf,op,kc) = 16KB staged by 2 gload_lds16/thread.
// k-slot swizzle f(r)=(r>>1)&3: conflict-free ds_read_b128 (verified R9: conflicts -> 0).
// R12 change: no forced lgkmcnt(0) before MFMA (compiler emits counted lgkm waits ->
// read tail overlaps MFMA cluster); vmcnt(4) at phases 4 and 8 ONLY (deadlines re-derived:
// each unit drains >=1 phase before first use, steady state and iter 0). sched_barrier(0)
// only at phase boundaries (after close barrier) to pin slot-reuse safety.
template<int KROW, int BUF, int KC, int MH, bool READB, int SBUF, int SOP, int SKC, bool DOVM>
__device__ __forceinline__ void gemm_phase(const unsigned short* __restrict__ A,
                                           const unsigned short* __restrict__ Bt,
                                           unsigned short (*lds)[2][2][8192],
                                           f32x4 (&acc)[8][4], short8 (&bfr)[4],
                                           int wr, int wc, int lane, int wid,
                                           int brow, int bcol, int stile)
{
    const unsigned short* aun = lds[BUF][0][KC];
    const unsigned short* bun = lds[BUF][1][KC];
    int ko = ((lane >> 4) ^ ((lane >> 1) & 3)) * 8;   // swizzled k-slot for this lane
    short8 af[4];
    #pragma unroll
    for (int mi = 0; mi < 4; ++mi) {
        int rowL = wr * 128 + (MH * 4 + mi) * 16 + (lane & 15);
        af[mi] = *(const short8*)&aun[rowL * 32 + ko];
    }
    if (READB) {
        #pragma unroll
        for (int ni = 0; ni < 4; ++ni) {
            int colL = wc * 64 + ni * 16 + (lane & 15);
            bfr[ni] = *(const short8*)&bun[colL * 32 + ko];
        }
    }
    // stage one unit (pre-swizzled global source, linear LDS dest)
    {
        const unsigned short* src = SOP ? Bt : A;
        int rbase = SOP ? bcol : brow;
        #pragma unroll
        for (int j = 0; j < 2; ++j) {
            int c = wid * 128 + j * 64 + lane;
            int row = c >> 2, k8 = c & 3;
            int k8s = k8 ^ ((row >> 1) & 3);
            const unsigned short* gp = src + (size_t)(rbase + row) * KROW
                                     + stile * 64 + SKC * 32 + k8s * 8;
            unsigned short* lp = lds[SBUF][SOP][SKC] + (wid * 128 + j * 64) * 8;
            gload_lds16(gp, lp);
        }
    }
    __builtin_amdgcn_s_barrier();
    __builtin_amdgcn_s_setprio(1);
    #pragma unroll
    for (int mi = 0; mi < 4; ++mi)
        #pragma unroll
        for (int ni = 0; ni < 4; ++ni)
            acc[MH * 4 + mi][ni] = __builtin_amdgcn_mfma_f32_16x16x32_bf16(
                af[mi], bfr[ni], acc[MH * 4 + mi][ni], 0, 0, 0);
    __builtin_amdgcn_s_setprio(0);
    if (DOVM) asm volatile("s_waitcnt vmcnt(4)" ::: "memory");
    __builtin_amdgcn_s_barrier();
    __builtin_amdgcn_sched_barrier(0);   // phase boundary: next phase's ds_reads stay below
}

// KROW: row stride of A and Bt; KLEN: K extent per wg (split-K slice); NCOLT: output
// 256-col tiles; SPLITK: slices (partial slabs of 4096*LDC fp32 each, concatenated).
// OUTMODE 0: C fp32.  2: Cb bf16.  3: Cb = h bf16 (ld 4096) + C = energy fp32 (ld 512).
// OUTMODE 4: writer-loss fused: Cb = hbf INPUT (masked h, ld 4096); C[bid] = block partial.
template<int KROW, int KLEN, int NCOLT, int SPLITK, int LDC, int OUTMODE>
__global__ __launch_bounds__(512, 1) void k_gemm8(const unsigned short* __restrict__ A,
                                                  const unsigned short* __restrict__ Bt,
                                                  float* __restrict__ C,
                                                  unsigned short* __restrict__ Cb)
{
    __shared__ unsigned short lds[2][2][2][8192];   // 128 KiB

    constexpr int KT   = KLEN / 64;
    constexpr int NIT  = KLEN / 128;
    constexpr int ROWT = 16;                        // 4096 / 256
    constexpr int NWG  = ROWT * NCOLT * SPLITK;     // must be % 8 == 0

    int tid = threadIdx.x;
    int wid = tid >> 6;
    int lane = tid & 63;
    int wr = wid >> 2, wc = wid & 3;

    int bid = blockIdx.x;
    int swz = (bid & 7) * (NWG / 8) + (bid >> 3);
    int ks   = swz / (ROWT * NCOLT);
    int tile = swz % (ROWT * NCOLT);
    int brow = (tile / NCOLT) * 256;
    int bcol = (tile % NCOLT) * 256;

    const unsigned short* Aofs = A + (size_t)ks * KLEN;
    const unsigned short* Bofs = Bt + (size_t)ks * KLEN;
    float* Cofs = C + (size_t)ks * 4096 * LDC;

    f32x4 acc[8][4] = {};
    short8 bfr[4];

    // ---- prologue: stage tile0 (4 units) + tile1.kc0 (2 units) ----
    auto stage0 = [&](int sbuf, int sop, int skc, int stile) {
        const unsigned short* src = sop ? Bofs : Aofs;
        int rbase = sop ? bcol : brow;
        #pragma unroll
        for (int j = 0; j < 2; ++j) {
            int c = wid * 128 + j * 64 + lane;
            int row = c >> 2, k8 = c & 3;
            int k8s = k8 ^ ((row >> 1) & 3);
            const unsigned short* gp = src + (size_t)(rbase + row) * KROW
                                     + stile * 64 + skc * 32 + k8s * 8;
            unsigned short* lp = lds[sbuf][sop][skc] + (wid * 128 + j * 64) * 8;
            gload_lds16(gp, lp);
        }
    };
    stage0(0, 0, 0, 0); stage0(0, 1, 0, 0);
    stage0(0, 0, 1, 0); stage0(0, 1, 1, 0);
    stage0(1, 0, 0, 1); stage0(1, 1, 0, 1);
    asm volatile("s_waitcnt vmcnt(4)" ::: "memory");   // drain tile0 kc0+kc1 (phases 1-4)
    __builtin_amdgcn_s_barrier();
    __builtin_amdgcn_sched_barrier(0);

    for (int i = 0; i < NIT; ++i) {
        int t1 = 2 * i + 1; if (t1 > KT - 1) t1 = KT - 1;
        int t2 = 2 * i + 2; if (t2 > KT - 1) t2 = KT - 1;
        int t3 = 2 * i + 3; if (t3 > KT - 1) t3 = KT - 1;
        gemm_phase<KROW, 0, 0, 0, true , 1, 0, 1, false>(Aofs, Bofs, lds, acc, bfr, wr, wc, lane, wid, brow, bcol, t1);
        gemm_phase<KROW, 0, 0, 1, false, 1, 1, 1, false>(Aofs, Bofs, lds, acc, bfr, wr, wc, lane, wid, brow, bcol, t1);
        gemm_phase<KROW, 0, 1, 0, true , 0, 0, 0, false>(Aofs, Bofs, lds, acc, bfr, wr, wc, lane, wid, brow, bcol, t2);
        gemm_phase<KROW, 0, 1, 1, false, 0, 1, 0, true >(Aofs, Bofs, lds, acc, bfr, wr, wc, lane, wid, brow, bcol, t2);
        gemm_phase<KROW, 1, 0, 0, true , 0, 0, 1, false>(Aofs, Bofs, lds, acc, bfr, wr, wc, lane, wid, brow, bcol, t2);
        gemm_phase<KROW, 1, 0, 1, false, 0, 1, 1, false>(Aofs, Bofs, lds, acc, bfr, wr, wc, lane, wid, brow, bcol, t2);
        gemm_phase<KROW, 1, 1, 0, true , 1, 0, 0, false>(Aofs, Bofs, lds, acc, bfr, wr, wc, lane, wid, brow, bcol, t3);
        gemm_phase<KROW, 1, 1, 1, false, 1, 1, 0, true >(Aofs, Bofs, lds, acc, bfr, wr, wc, lane, wid, brow, bcol, t3);
    }

    // epilogue: C/D layout col=lane&15, row=(lane>>4)*4+reg  [verified m89/m91]
    if (OUTMODE == 0 || OUTMODE == 2) {
        #pragma unroll
        for (int mr = 0; mr < 8; ++mr) {
            int row0 = brow + wr * 128 + mr * 16 + (lane >> 4) * 4;
            #pragma unroll
            for (int nr = 0; nr < 4; ++nr) {
                int col = bcol + wc * 64 + nr * 16 + (lane & 15);
                #pragma unroll
                for (int r = 0; r < 4; ++r) {
                    if (OUTMODE == 0)
                        Cofs[(size_t)(row0 + r) * LDC + col] = acc[mr][nr][r];
                    else
                        Cb[(size_t)(row0 + r) * LDC + col] = f2b(acc[mr][nr][r]);
                }
            }
        }
    } else if (OUTMODE == 3) {
        #pragma unroll
        for (int mr = 0; mr < 8; ++mr) {
            int row0 = brow + wr * 128 + mr * 16 + (lane >> 4) * 4;
            #pragma unroll
            for (int nr = 0; nr < 4; ++nr) {
                int col = bcol + wc * 64 + nr * 16 + (lane & 15);
                f32x4 a = acc[mr][nr];
                #pragma unroll
                for (int r = 0; r < 4; ++r)
                    Cb[(size_t)(row0 + r) * 4096 + col] = f2b(a[r]);
                // energy: sum h^2 over the 8-lane b-group (3x shfl_xor tree)
                f32x4 sq;
                #pragma unroll
                for (int r = 0; r < 4; ++r) sq[r] = a[r] * a[r];
                #pragma unroll
                for (int off = 1; off <= 4; off <<= 1) {
                    sq[0] += __shfl_xor(sq[0], off);
                    sq[1] += __shfl_xor(sq[1], off);
                    sq[2] += __shfl_xor(sq[2], off);
                    sq[3] += __shfl_xor(sq[3], off);
                }
                if ((lane & 7) == 0) {
                    int e = ((bcol + wc * 64 + nr * 16) >> 3) + ((lane >> 3) & 1);
                    #pragma unroll
                    for (int r = 0; r < 4; ++r)
                        C[(size_t)(row0 + r) * 512 + e] = sq[r];
                }
            }
        }
    } else {  // OUTMODE 4: writer loss partial, no hrecon materialization
        float local = 0.f;
        #pragma unroll
        for (int mr = 0; mr < 8; ++mr) {
            int row0 = brow + wr * 128 + mr * 16 + (lane >> 4) * 4;
            #pragma unroll
            for (int nr = 0; nr < 4; ++nr) {
                int col = bcol + wc * 64 + nr * 16 + (lane & 15);
                #pragma unroll
                for (int r = 0; r < 4; ++r) {
                    unsigned short hbits = Cb[(size_t)(row0 + r) * 4096 + col];
                    if (hbits & 0x7fffu) {
                        float d = acc[mr][nr][r] - b2f(hbits);
                        local += d * d;
                    }
                }
            }
        }
        __syncthreads();                 // LDS dead after K-loop; reuse for reduction
        float* red = (float*)lds;
        red[tid] = local;
        __syncthreads();
        for (int s = 256; s > 0; s >>= 1) {
            if (tid < s) red[tid] += red[tid + s];
            __syncthreads();
        }
        if (tid == 0) C[bid] = red[0];
    }
}

// ---- top-16 from energy; mask hbf in place (one wave per token) ----
__global__ __launch_bounds__(256) void k_topk2(const float* __restrict__ energy,
                                               unsigned short* __restrict__ hbf,
                                               int* __restrict__ topk_idx,
                                               int* __restrict__ counts)
{
    int wave = threadIdx.x >> 6;
    int lane = threadIdx.x & 63;
    int n = blockIdx.x * 4 + wave;
    float ev[8];
    #pragma unroll
    for (int i = 0; i < 8; ++i) ev[i] = energy[(size_t)n * M_EXP + i * 64 + lane];
    for (int r = 0; r < K_TOP; ++r) {
        float bv = -1.0f; int bi = 0;
        #pragma unroll
        for (int i = 0; i < 8; ++i) {
            if (ev[i] > bv) { bv = ev[i]; bi = i * 64 + lane; }
        }
        #pragma unroll
        for (int off = 1; off < 64; off <<= 1) {
            float ov = __shfl_xor(bv, off);
            int   oi = __shfl_xor(bi, off);
            if (ov > bv || (ov == bv && oi < bi)) { bv = ov; bi = oi; }
        }
        if (lane == 0) {
            topk_idx[n * K_TOP + r] = bi;
            atomicAdd(&counts[bi], 1);
        }
        #pragma unroll
        for (int i = 0; i < 8; ++i)
            if (((bi >> 6) == i) && (lane == (bi & 63))) ev[i] = -INFINITY;
    }
    // zero non-selected experts' h (selected entries already hold h from GEMM1)
    ushort8 z = {0, 0, 0, 0, 0, 0, 0, 0};
    #pragma unroll
    for (int i = 0; i < 8; ++i) {
        int e = i * 64 + lane;
        if (ev[i] != -INFINITY)
            *(ushort8*)&hbf[(size_t)n * MB + e * 8] = z;
    }
}

// ---- fused: reduce 4 split-K partials + x_out + uncap + writesb (one token/block) ----
__global__ __launch_bounds__(256) void k_reduce_fin(const float* __restrict__ P,
                                                    const float* __restrict__ xn,
                                                    float* __restrict__ x_out,
                                                    unsigned short* __restrict__ wb,
                                                    float* __restrict__ uncap)
{
    const size_t S = (size_t)4096 * 1024;
    int n = blockIdx.x;
    int t = threadIdx.x;
    int c = t * 4;                               // 0..1023, step 4
    size_t base = (size_t)n * 1024 + c;
    float4 a = *(const float4*)&P[base];
    float4 b = *(const float4*)&P[base + S];
    float4 cc = *(const float4*)&P[base + 2 * S];
    float4 d = *(const float4*)&P[base + 3 * S];
    float4 v = make_float4(a.x + b.x + cc.x + d.x, a.y + b.y + cc.y + d.y,
                           a.z + b.z + cc.z + d.z, a.w + b.w + cc.w + d.w);
    bool isW = (c < 512);
    int xc = isW ? c : (c - 512);
    float4 xv = *(const float4*)&xn[(size_t)n * D_DIM + xc];
    float4 yr;                                    // y (writes half) or resid (xhat half)
    if (isW) yr = make_float4(xv.x + v.x, xv.y + v.y, xv.z + v.z, xv.w + v.w);
    else     yr = make_float4(xv.x - v.x, xv.y - v.y, xv.z - v.z, xv.w - v.w);
    float local = yr.x*yr.x + yr.y*yr.y + yr.z*yr.z + yr.w*yr.w;

    __shared__ float red[256];
    __shared__ float sinv;
    red[t] = local;
    __syncthreads();
    for (int s = 64; s > 0; s >>= 1) {
        if ((t & 127) < s) red[t] += red[t + s];
        __syncthreads();
    }
    if (t == 0) {
        uncap[n] = red[128];                      // sum resid^2
        sinv = 1.0f / fmaxf(sqrtf(red[0]), EPSV); // from sum y^2
    }
    __syncthreads();
    if (isW) {
        float inv = sinv;
        *(float4*)&x_out[(size_t)n * D_DIM + c] =
            make_float4(yr.x*inv, yr.y*inv, yr.z*inv, yr.w*inv);
        ushort4v o;
        o[0] = f2b(yr.x); o[1] = f2b(yr.y); o[2] = f2b(yr.z); o[3] = f2b(yr.w);
        *(ushort4v*)&wb[(size_t)n * 512 + c] = o;
    }
}

// ---------------- final scalar reductions + counts ----------------
__global__ __launch_bounds__(256) void k_finalize(const float* __restrict__ uncap,
                                                  const float* __restrict__ writer_part,
                                                  const int* __restrict__ counts,
                                                  float* __restrict__ out)
{
    __shared__ float ru[256], rw[256];
    int t = threadIdx.x;
    float su = 0.f;
    for (int i = t; i < N_TOK; i += 256) su += uncap[i];
    float sw = writer_part[t];                    // exactly 256 partials
    ru[t] = su; rw[t] = sw;
    __syncthreads();
    for (int s = 128; s > 0; s >>= 1) {
        if (t < s) { ru[t] += ru[t + s]; rw[t] += rw[t + s]; }
        __syncthreads();
    }
    if (t == 0)
        out[(size_t)N_TOK * D_DIM] = ru[0] / (float)N_TOK
                                   + rw[0] / (float)(N_TOK * K_TOP * B_DIM);
    for (int i = t; i < M_EXP; i += 256)
        out[(size_t)N_TOK * D_DIM + 1 + i] = (float)counts[i];
}

extern "C" void kernel_launch(void* const* d_in, const int* in_sizes, int n_in,
                              void* d_out, int out_size, void* d_ws, size_t ws_size,
                              hipStream_t stream)
{
    const float* x = (const float*)d_in[0];
    const float* V = (const float*)d_in[1];
    const float* U = (const float*)d_in[2];
    float* out = (float*)d_out;

    float* ws     = (float*)d_ws;
    float* xn     = ws;                        // 2,097,152 f  (8.4 MB)
    float* P      = xn + 2097152;              // 16,777,216 f (67.1 MB): GEMM1 energy,
                                               //   then GEMM23 split-K partials
    float* uncap  = P + 16777216;              // 4096 f
    float* writer_part = uncap + 4096;         // 256 f (+pad)
    int*   topk_i = (int*)(writer_part + 512); // 65,536 i
    int*   counts = topk_i + 65536;            // 512 i (+pad)
    float* partV  = (float*)(counts + 1024);   // 65,536 f
    float* partU  = partV + 65536;             // 65,536 f
    unsigned short* hbf = (unsigned short*)(partU + 65536);  // 16,777,216 us (33.6 MB)
    unsigned short* U2t = hbf + 16777216;      // 2,097,152 us (4.2 MB)
    unsigned short* WXt = U2t + 2097152;       // 4,194,304 us (8.4 MB)
    unsigned short* R   = WXt + 4194304;       // 12,582,912 us (25.2 MB)
    unsigned short* Abf  = R;                  // 6,291,456 us (gemm1 A')
    unsigned short* Btbf = R + 6291456;        // 6,291,456 us (gemm1 B')
    unsigned short* writesb = R;               // 2,097,152 us (aliases Abf after GEMM1)
    float* energy = P;                         // 2,097,152 f ⊂ P
    // total ws use ~148 MB

    k_norm_x_part<<<1536, 256, 0, stream>>>(x, xn, Abf, counts, V, U, partV, partU);
    k_norm_UV2  <<<512, 256, 0, stream>>>(V, U, partV, partU, Btbf, WXt, U2t);
    // GEMM1: h = A'(4096x1536) @ B'(1536x4096) -> hbf bf16 + energy fp32 (epilogue-fused)
    k_gemm8<KTOT, KTOT, 16, 1, 4096, 3><<<256, 512, 0, stream>>>(Abf, Btbf, energy, hbf);
    k_topk2     <<<N_TOK / 4, 256, 0, stream>>>(energy, hbf, topk_i, counts);
    // GEMM23: partial[ks] = hbf(4096x4096, K-slice ks) @ WXt^T -> 4x(4096x1024) in P
    k_gemm8<4096, 1024, 4, 4, 1024, 0><<<256, 512, 0, stream>>>(hbf, WXt, P, nullptr);
    // fused reduce + x_out + uncap + writes bf16
    k_reduce_fin<<<4096, 256, 0, stream>>>(P, xn, out, writesb, uncap);
    // GEMM4 fused writer-loss: hrecon tile vs hbf, per-block partials (no hrecon write)
    k_gemm8<D_DIM, D_DIM, 16, 1, 4096, 4><<<256, 512, 0, stream>>>(writesb, U2t, writer_part, hbf);
    k_finalize  <<<1, 256, 0, stream>>>(uncap, writer_part, counts, out);
}

// Round 13
// 210.708 us; speedup vs baseline: 1.0788x; 1.0108x over previous
//
#include <hip/hip_runtime.h>
#include <math.h>

#define N_TOK 4096
#define D_DIM 512
#define M_EXP 512
#define B_DIM 8
#define K_TOP 16
#define MB    4096          // M_EXP * B_DIM
#define UROW  4104          // (D_DIM+1) * B_DIM
#define EPSV  1e-8f
#define KTOT  1536          // 3 * D (split-bf16 K blocks for GEMM1)

typedef unsigned short ushort8 __attribute__((ext_vector_type(8)));
typedef unsigned short ushort4v __attribute__((ext_vector_type(4)));
typedef short short8 __attribute__((ext_vector_type(8)));
typedef float f32x4 __attribute__((ext_vector_type(4)));

__device__ inline float b2f(unsigned short u) {
    union { unsigned int i; float f; } c;
    c.i = ((unsigned int)u) << 16;
    return c.f;
}
__device__ inline unsigned short f2b(float f) {     // RNE bf16
    union { float f; unsigned int i; } c; c.f = f;
    unsigned int lsb = (c.i >> 16) & 1;
    c.i += 0x7fffu + lsb;
    return (unsigned short)(c.i >> 16);
}
__device__ inline unsigned short f2h(float f) {     // RNE fp16 via _Float16
    union { _Float16 h; unsigned short u; } c;
    c.h = (_Float16)f;
    return c.u;
}
__device__ inline float h2f(unsigned short u) {
    union { _Float16 h; unsigned short u; } c;
    c.u = u;
    return (float)c.h;
}
__device__ inline void gload_lds16(const unsigned short* g, unsigned short* l) {
    __builtin_amdgcn_global_load_lds(
        (const __attribute__((address_space(1))) unsigned int*)g,
        (__attribute__((address_space(3))) unsigned int*)l, 16, 0, 0);
}

// --- merged: blocks 0-1023 normalize x rows (+Abf); 1024-1535 V/U norm partials ---
__global__ __launch_bounds__(256) void k_norm_x_part(const float* __restrict__ x,
                                                     float* __restrict__ xn,
                                                     unsigned short* __restrict__ Abf,
                                                     int* __restrict__ counts,
                                                     const float* __restrict__ V,
                                                     const float* __restrict__ U,
                                                     float* __restrict__ partV,
                                                     float* __restrict__ partU)
{
    int blk = blockIdx.x;
    if (blk < 1024) {
        if (blk == 0) {
            counts[threadIdx.x] = 0;
            counts[threadIdx.x + 256] = 0;
        }
        int wave = threadIdx.x >> 6;
        int lane = threadIdx.x & 63;
        int n = blk * 4 + wave;
        const float4* xp = (const float4*)&x[(size_t)n * D_DIM + lane * 8];
        float4 a = xp[0], b = xp[1];
        float s = a.x*a.x + a.y*a.y + a.z*a.z + a.w*a.w
                + b.x*b.x + b.y*b.y + b.z*b.z + b.w*b.w;
        #pragma unroll
        for (int off = 1; off < 64; off <<= 1) s += __shfl_xor(s, off);
        float inv = 1.0f / fmaxf(sqrtf(s), EPSV);
        float v[8] = {a.x*inv, a.y*inv, a.z*inv, a.w*inv,
                      b.x*inv, b.y*inv, b.z*inv, b.w*inv};
        float4* op = (float4*)&xn[(size_t)n * D_DIM + lane * 8];
        op[0] = make_float4(v[0], v[1], v[2], v[3]);
        op[1] = make_float4(v[4], v[5], v[6], v[7]);
        ushort8 hi, lo;
        #pragma unroll
        for (int j = 0; j < 8; ++j) {
            unsigned short h = f2b(v[j]);
            hi[j] = h;
            lo[j] = f2b(v[j] - b2f(h));
        }
        size_t base = (size_t)n * KTOT + lane * 8;
        *(ushort8*)&Abf[base]        = hi;
        *(ushort8*)&Abf[base + 512]  = hi;
        *(ushort8*)&Abf[base + 1024] = lo;
    } else if (blk < 1280) {
        blk -= 1024;
        int s = blk >> 4;
        int t = (blk & 15) * 256 + threadIdx.x;
        float sum = 0.f;
        int d0 = s * 32;
        #pragma unroll 8
        for (int d = d0; d < d0 + 32; ++d) {
            float v = V[(size_t)d * MB + t];
            sum += v * v;
        }
        partV[(size_t)s * MB + t] = sum;
    } else {
        blk -= 1280;
        int s = blk >> 4;
        int t = (blk & 15) * 256 + threadIdx.x;
        int m = t >> 3, b = t & 7;
        size_t base = (size_t)m * UROW + b;
        int pbeg = s * 32;
        int pend = (s == 15) ? 513 : pbeg + 32;
        float sum = 0.f;
        for (int p = pbeg; p < pend; ++p) {
            float u = U[base + (size_t)p * 8];
            sum += u * u;
        }
        partU[(size_t)s * MB + t] = sum;
    }
}

// ---- merged normalize+emit: blocks 0-255 -> V path, 256-511 -> U path ----
__global__ __launch_bounds__(256) void k_norm_UV2(const float* __restrict__ V,
                                                  const float* __restrict__ U,
                                                  const float* __restrict__ partV,
                                                  const float* __restrict__ partU,
                                                  unsigned short* __restrict__ Btbf,
                                                  unsigned short* __restrict__ WXt,
                                                  unsigned short* __restrict__ U2t)
{
    int blk = blockIdx.x;
    if (blk < 256) {
        int s = blk >> 4;
        int t = (blk & 15) * 256 + threadIdx.x;
        float n2 = 0.f;
        #pragma unroll
        for (int i = 0; i < 16; ++i) n2 += partV[(size_t)i * MB + t];
        float inv = 1.0f / fmaxf(sqrtf(n2), EPSV);
        size_t row = (size_t)t * KTOT;
        int dbeg = s * 32;
        for (int d0 = dbeg; d0 < dbeg + 32; d0 += 8) {
            ushort8 hi, lo;
            #pragma unroll
            for (int j = 0; j < 8; ++j) {
                float f = V[(size_t)(d0 + j) * MB + t] * inv;
                unsigned short h = f2b(f);
                hi[j] = h;
                lo[j] = f2b(f - b2f(h));
                WXt[(size_t)(512 + d0 + j) * MB + t] = h;
            }
            *(ushort8*)&Btbf[row + d0]        = hi;
            *(ushort8*)&Btbf[row + 512 + d0]  = lo;
            *(ushort8*)&Btbf[row + 1024 + d0] = hi;
        }
    } else {
        blk -= 256;
        int s = blk >> 4;
        int t = (blk & 15) * 256 + threadIdx.x;
        int m = t >> 3, b = t & 7;
        size_t base = (size_t)m * UROW + b;
        float n2 = 0.f;
        #pragma unroll
        for (int i = 0; i < 16; ++i) n2 += partU[(size_t)i * MB + t];
        float inv = 1.0f / fmaxf(sqrtf(n2), EPSV);
        int pbeg = s * 32;
        for (int p0 = pbeg; p0 < pbeg + 32; p0 += 8) {
            ushort8 h8;
            #pragma unroll
            for (int j = 0; j < 8; ++j) {
                unsigned short h = f2b(U[base + (size_t)(p0 + j) * 8] * inv);
                h8[j] = h;
                WXt[(size_t)(p0 + j) * MB + t] = h;
            }
            *(ushort8*)&U2t[(size_t)t * D_DIM + p0] = h8;
        }
    }
}

// ================== 8-phase 256x256 bf16 GEMM (T3+T4+T5, k-slot swizzle) ==================
// A row-major (4096 x KROW), Bt col-major (Bt[col*KROW + k]).
// LDS: lds[buf][op][kc][row*32 + k], unit (buf,op,kc) = 16KB staged by 2 gload_lds16/thread.
// k-slot swizzle f(r)=(r>>1)&3: conflict-free ds_read_b128 (verified R9: conflicts -> 0).
// Counted compiler lgkm waits (no forced lgkmcnt(0)); vmcnt(4) at phases 4 and 8 only.
template<int KROW, int BUF, int KC, int MH, bool READB, int SBUF, int SOP, int SKC, bool DOVM>
__device__ __forceinline__ void gemm_phase(const unsigned short* __restrict__ A,
                                           const unsigned short* __restrict__ Bt,
                                           unsigned short (*lds)[2][2][8192],
                                           f32x4 (&acc)[8][4], short8 (&bfr)[4],
                                           int wr, int wc, int lane, int wid,
                                           int brow, int bcol, int stile)
{
    const unsigned short* aun = lds[BUF][0][KC];
    const unsigned short* bun = lds[BUF][1][KC];
    int ko = ((lane >> 4) ^ ((lane >> 1) & 3)) * 8;   // swizzled k-slot for this lane
    short8 af[4];
    #pragma unroll
    for (int mi = 0; mi < 4; ++mi) {
        int rowL = wr * 128 + (MH * 4 + mi) * 16 + (lane & 15);
        af[mi] = *(const short8*)&aun[rowL * 32 + ko];
    }
    if (READB) {
        #pragma unroll
        for (int ni = 0; ni < 4; ++ni) {
            int colL = wc * 64 + ni * 16 + (lane & 15);
            bfr[ni] = *(const short8*)&bun[colL * 32 + ko];
        }
    }
    // stage one unit (pre-swizzled global source, linear LDS dest)
    {
        const unsigned short* src = SOP ? Bt : A;
        int rbase = SOP ? bcol : brow;
        #pragma unroll
        for (int j = 0; j < 2; ++j) {
            int c = wid * 128 + j * 64 + lane;
            int row = c >> 2, k8 = c & 3;
            int k8s = k8 ^ ((row >> 1) & 3);
            const unsigned short* gp = src + (size_t)(rbase + row) * KROW
                                     + stile * 64 + SKC * 32 + k8s * 8;
            unsigned short* lp = lds[SBUF][SOP][SKC] + (wid * 128 + j * 64) * 8;
            gload_lds16(gp, lp);
        }
    }
    __builtin_amdgcn_s_barrier();
    __builtin_amdgcn_s_setprio(1);
    #pragma unroll
    for (int mi = 0; mi < 4; ++mi)
        #pragma unroll
        for (int ni = 0; ni < 4; ++ni)
            acc[MH * 4 + mi][ni] = __builtin_amdgcn_mfma_f32_16x16x32_bf16(
                af[mi], bfr[ni], acc[MH * 4 + mi][ni], 0, 0, 0);
    __builtin_amdgcn_s_setprio(0);
    if (DOVM) asm volatile("s_waitcnt vmcnt(4)" ::: "memory");
    __builtin_amdgcn_s_barrier();
    __builtin_amdgcn_sched_barrier(0);   // phase boundary: next phase's ds_reads stay below
}

// KROW: row stride of A and Bt; KLEN: K extent per wg (split-K slice); NCOLT: output
// 256-col tiles; SPLITK: slices.
// OUTMODE 0: C fp32 (slabs of 4096*LDC).  2: Cb bf16.
// OUTMODE 3: Cb = h bf16 (ld 4096) + C = energy fp32 (ld 512).
// OUTMODE 4: writer-loss fused: Cb = hbf INPUT (masked h, ld 4096); C[bid] = block partial.
// OUTMODE 5: split partials: col<512 -> C fp32 slab (ld 512); col>=512 -> Cb fp16 slab (ld 512).
template<int KROW, int KLEN, int NCOLT, int SPLITK, int LDC, int OUTMODE>
__global__ __launch_bounds__(512, 1) void k_gemm8(const unsigned short* __restrict__ A,
                                                  const unsigned short* __restrict__ Bt,
                                                  float* __restrict__ C,
                                                  unsigned short* __restrict__ Cb)
{
    __shared__ unsigned short lds[2][2][2][8192];   // 128 KiB

    constexpr int KT   = KLEN / 64;
    constexpr int NIT  = KLEN / 128;
    constexpr int ROWT = 16;                        // 4096 / 256
    constexpr int NWG  = ROWT * NCOLT * SPLITK;     // must be % 8 == 0

    int tid = threadIdx.x;
    int wid = tid >> 6;
    int lane = tid & 63;
    int wr = wid >> 2, wc = wid & 3;

    int bid = blockIdx.x;
    int brow, bcol, ks;
    if constexpr (NCOLT == 16 && SPLITK == 1) {
        // L2-friendly 4x8 chunk per XCD: XCD x owns rows [(x&3)*4,+4) x cols [(x>>2)*8,+8)
        int x = bid & 7, p = bid >> 3;              // p in [0,32)
        brow = ((x & 3) * 4 + (p >> 3)) * 256;
        bcol = ((x >> 2) * 8 + (p & 7)) * 256;
        ks = 0;
    } else {
        int swz = (bid & 7) * (NWG / 8) + (bid >> 3);
        ks   = swz / (ROWT * NCOLT);
        int tile = swz % (ROWT * NCOLT);
        brow = (tile / NCOLT) * 256;
        bcol = (tile % NCOLT) * 256;
    }

    const unsigned short* Aofs = A + (size_t)ks * KLEN;
    const unsigned short* Bofs = Bt + (size_t)ks * KLEN;
    float* Cofs = C + (size_t)ks * 4096 * LDC;
    unsigned short* Xofs = (OUTMODE == 5) ? (Cb + (size_t)ks * 4096 * 512) : Cb;

    f32x4 acc[8][4] = {};
    short8 bfr[4];

    // ---- prologue: stage tile0 (4 units) + tile1.kc0 (2 units) ----
    auto stage0 = [&](int sbuf, int sop, int skc, int stile) {
        const unsigned short* src = sop ? Bofs : Aofs;
        int rbase = sop ? bcol : brow;
        #pragma unroll
        for (int j = 0; j < 2; ++j) {
            int c = wid * 128 + j * 64 + lane;
            int row = c >> 2, k8 = c & 3;
            int k8s = k8 ^ ((row >> 1) & 3);
            const unsigned short* gp = src + (size_t)(rbase + row) * KROW
                                     + stile * 64 + skc * 32 + k8s * 8;
            unsigned short* lp = lds[sbuf][sop][skc] + (wid * 128 + j * 64) * 8;
            gload_lds16(gp, lp);
        }
    };
    stage0(0, 0, 0, 0); stage0(0, 1, 0, 0);
    stage0(0, 0, 1, 0); stage0(0, 1, 1, 0);
    stage0(1, 0, 0, 1); stage0(1, 1, 0, 1);
    asm volatile("s_waitcnt vmcnt(4)" ::: "memory");   // drain tile0 kc0+kc1 (phases 1-4)
    __builtin_amdgcn_s_barrier();
    __builtin_amdgcn_sched_barrier(0);

    for (int i = 0; i < NIT; ++i) {
        int t1 = 2 * i + 1; if (t1 > KT - 1) t1 = KT - 1;
        int t2 = 2 * i + 2; if (t2 > KT - 1) t2 = KT - 1;
        int t3 = 2 * i + 3; if (t3 > KT - 1) t3 = KT - 1;
        gemm_phase<KROW, 0, 0, 0, true , 1, 0, 1, false>(Aofs, Bofs, lds, acc, bfr, wr, wc, lane, wid, brow, bcol, t1);
        gemm_phase<KROW, 0, 0, 1, false, 1, 1, 1, false>(Aofs, Bofs, lds, acc, bfr, wr, wc, lane, wid, brow, bcol, t1);
        gemm_phase<KROW, 0, 1, 0, true , 0, 0, 0, false>(Aofs, Bofs, lds, acc, bfr, wr, wc, lane, wid, brow, bcol, t2);
        gemm_phase<KROW, 0, 1, 1, false, 0, 1, 0, true >(Aofs, Bofs, lds, acc, bfr, wr, wc, lane, wid, brow, bcol, t2);
        gemm_phase<KROW, 1, 0, 0, true , 0, 0, 1, false>(Aofs, Bofs, lds, acc, bfr, wr, wc, lane, wid, brow, bcol, t2);
        gemm_phase<KROW, 1, 0, 1, false, 0, 1, 1, false>(Aofs, Bofs, lds, acc, bfr, wr, wc, lane, wid, brow, bcol, t2);
        gemm_phase<KROW, 1, 1, 0, true , 1, 0, 0, false>(Aofs, Bofs, lds, acc, bfr, wr, wc, lane, wid, brow, bcol, t3);
        gemm_phase<KROW, 1, 1, 1, false, 1, 1, 0, true >(Aofs, Bofs, lds, acc, bfr, wr, wc, lane, wid, brow, bcol, t3);
    }

    // epilogue: C/D layout col=lane&15, row=(lane>>4)*4+reg  [verified m89/m91]
    if (OUTMODE == 0 || OUTMODE == 2) {
        #pragma unroll
        for (int mr = 0; mr < 8; ++mr) {
            int row0 = brow + wr * 128 + mr * 16 + (lane >> 4) * 4;
            #pragma unroll
            for (int nr = 0; nr < 4; ++nr) {
                int col = bcol + wc * 64 + nr * 16 + (lane & 15);
                #pragma unroll
                for (int r = 0; r < 4; ++r) {
                    if (OUTMODE == 0)
                        Cofs[(size_t)(row0 + r) * LDC + col] = acc[mr][nr][r];
                    else
                        Cb[(size_t)(row0 + r) * LDC + col] = f2b(acc[mr][nr][r]);
                }
            }
        }
    } else if (OUTMODE == 5) {
        #pragma unroll
        for (int mr = 0; mr < 8; ++mr) {
            int row0 = brow + wr * 128 + mr * 16 + (lane >> 4) * 4;
            #pragma unroll
            for (int nr = 0; nr < 4; ++nr) {
                int col = bcol + wc * 64 + nr * 16 + (lane & 15);
                #pragma unroll
                for (int r = 0; r < 4; ++r) {
                    float v = acc[mr][nr][r];
                    if (col < 512)
                        Cofs[(size_t)(row0 + r) * 512 + col] = v;
                    else
                        Xofs[(size_t)(row0 + r) * 512 + (col - 512)] = f2h(v);
                }
            }
        }
    } else if (OUTMODE == 3) {
        #pragma unroll
        for (int mr = 0; mr < 8; ++mr) {
            int row0 = brow + wr * 128 + mr * 16 + (lane >> 4) * 4;
            #pragma unroll
            for (int nr = 0; nr < 4; ++nr) {
                int col = bcol + wc * 64 + nr * 16 + (lane & 15);
                f32x4 a = acc[mr][nr];
                #pragma unroll
                for (int r = 0; r < 4; ++r)
                    Cb[(size_t)(row0 + r) * 4096 + col] = f2b(a[r]);
                // energy: sum h^2 over the 8-lane b-group (3x shfl_xor tree)
                f32x4 sq;
                #pragma unroll
                for (int r = 0; r < 4; ++r) sq[r] = a[r] * a[r];
                #pragma unroll
                for (int off = 1; off <= 4; off <<= 1) {
                    sq[0] += __shfl_xor(sq[0], off);
                    sq[1] += __shfl_xor(sq[1], off);
                    sq[2] += __shfl_xor(sq[2], off);
                    sq[3] += __shfl_xor(sq[3], off);
                }
                if ((lane & 7) == 0) {
                    int e = ((bcol + wc * 64 + nr * 16) >> 3) + ((lane >> 3) & 1);
                    #pragma unroll
                    for (int r = 0; r < 4; ++r)
                        C[(size_t)(row0 + r) * 512 + e] = sq[r];
                }
            }
        }
    } else {  // OUTMODE 4: writer loss partial, no hrecon materialization
        float local = 0.f;
        #pragma unroll
        for (int mr = 0; mr < 8; ++mr) {
            int row0 = brow + wr * 128 + mr * 16 + (lane >> 4) * 4;
            #pragma unroll
            for (int nr = 0; nr < 4; ++nr) {
                int col = bcol + wc * 64 + nr * 16 + (lane & 15);
                #pragma unroll
                for (int r = 0; r < 4; ++r) {
                    unsigned short hbits = Cb[(size_t)(row0 + r) * 4096 + col];
                    if (hbits & 0x7fffu) {
                        float d = acc[mr][nr][r] - b2f(hbits);
                        local += d * d;
                    }
                }
            }
        }
        __syncthreads();                 // LDS dead after K-loop; reuse for reduction
        float* red = (float*)lds;
        red[tid] = local;
        __syncthreads();
        for (int s = 256; s > 0; s >>= 1) {
            if (tid < s) red[tid] += red[tid + s];
            __syncthreads();
        }
        if (tid == 0) C[bid] = red[0];
    }
}

// ---- top-16 from energy; mask hbf in place (one wave per token) ----
__global__ __launch_bounds__(256) void k_topk2(const float* __restrict__ energy,
                                               unsigned short* __restrict__ hbf,
                                               int* __restrict__ topk_idx,
                                               int* __restrict__ counts)
{
    int wave = threadIdx.x >> 6;
    int lane = threadIdx.x & 63;
    int n = blockIdx.x * 4 + wave;
    float ev[8];
    #pragma unroll
    for (int i = 0; i < 8; ++i) ev[i] = energy[(size_t)n * M_EXP + i * 64 + lane];
    for (int r = 0; r < K_TOP; ++r) {
        float bv = -1.0f; int bi = 0;
        #pragma unroll
        for (int i = 0; i < 8; ++i) {
            if (ev[i] > bv) { bv = ev[i]; bi = i * 64 + lane; }
        }
        #pragma unroll
        for (int off = 1; off < 64; off <<= 1) {
            float ov = __shfl_xor(bv, off);
            int   oi = __shfl_xor(bi, off);
            if (ov > bv || (ov == bv && oi < bi)) { bv = ov; bi = oi; }
        }
        if (lane == 0) {
            topk_idx[n * K_TOP + r] = bi;
            atomicAdd(&counts[bi], 1);
        }
        #pragma unroll
        for (int i = 0; i < 8; ++i)
            if (((bi >> 6) == i) && (lane == (bi & 63))) ev[i] = -INFINITY;
    }
    // zero non-selected experts' h (selected entries already hold h from GEMM1)
    ushort8 z = {0, 0, 0, 0, 0, 0, 0, 0};
    #pragma unroll
    for (int i = 0; i < 8; ++i) {
        int e = i * 64 + lane;
        if (ev[i] != -INFINITY)
            *(ushort8*)&hbf[(size_t)n * MB + e * 8] = z;
    }
}

// ---- fused: reduce 4 split-K partials (W fp32, X fp16) + x_out + uncap + writesb ----
__global__ __launch_bounds__(256) void k_reduce_fin(const float* __restrict__ Wp,
                                                    const unsigned short* __restrict__ Xp,
                                                    const float* __restrict__ xn,
                                                    float* __restrict__ x_out,
                                                    unsigned short* __restrict__ wb,
                                                    float* __restrict__ uncap)
{
    const size_t S = (size_t)4096 * 512;
    int n = blockIdx.x;
    int t = threadIdx.x;
    int c = t * 4;                               // 0..1023, step 4
    bool isW = (c < 512);
    int xc = isW ? c : (c - 512);
    float4 v;
    if (isW) {
        size_t base = (size_t)n * 512 + c;
        float4 a = *(const float4*)&Wp[base];
        float4 b = *(const float4*)&Wp[base + S];
        float4 cc = *(const float4*)&Wp[base + 2 * S];
        float4 d = *(const float4*)&Wp[base + 3 * S];
        v = make_float4(a.x + b.x + cc.x + d.x, a.y + b.y + cc.y + d.y,
                        a.z + b.z + cc.z + d.z, a.w + b.w + cc.w + d.w);
    } else {
        size_t base = (size_t)n * 512 + xc;
        ushort4v a = *(const ushort4v*)&Xp[base];
        ushort4v b = *(const ushort4v*)&Xp[base + S];
        ushort4v cc = *(const ushort4v*)&Xp[base + 2 * S];
        ushort4v d = *(const ushort4v*)&Xp[base + 3 * S];
        v = make_float4(h2f(a[0]) + h2f(b[0]) + h2f(cc[0]) + h2f(d[0]),
                        h2f(a[1]) + h2f(b[1]) + h2f(cc[1]) + h2f(d[1]),
                        h2f(a[2]) + h2f(b[2]) + h2f(cc[2]) + h2f(d[2]),
                        h2f(a[3]) + h2f(b[3]) + h2f(cc[3]) + h2f(d[3]));
    }
    float4 xv = *(const float4*)&xn[(size_t)n * D_DIM + xc];
    float4 yr;                                    // y (writes half) or resid (xhat half)
    if (isW) yr = make_float4(xv.x + v.x, xv.y + v.y, xv.z + v.z, xv.w + v.w);
    else     yr = make_float4(xv.x - v.x, xv.y - v.y, xv.z - v.z, xv.w - v.w);
    float local = yr.x*yr.x + yr.y*yr.y + yr.z*yr.z + yr.w*yr.w;

    __shared__ float red[256];
    __shared__ float sinv;
    red[t] = local;
    __syncthreads();
    for (int s = 64; s > 0; s >>= 1) {
        if ((t & 127) < s) red[t] += red[t + s];
        __syncthreads();
    }
    if (t == 0) {
        uncap[n] = red[128];                      // sum resid^2
        sinv = 1.0f / fmaxf(sqrtf(red[0]), EPSV); // from sum y^2
    }
    __syncthreads();
    if (isW) {
        float inv = sinv;
        *(float4*)&x_out[(size_t)n * D_DIM + c] =
            make_float4(yr.x*inv, yr.y*inv, yr.z*inv, yr.w*inv);
        ushort4v o;
        o[0] = f2b(yr.x); o[1] = f2b(yr.y); o[2] = f2b(yr.z); o[3] = f2b(yr.w);
        *(ushort4v*)&wb[(size_t)n * 512 + c] = o;
    }
}

// ---------------- final scalar reductions + counts ----------------
__global__ __launch_bounds__(256) void k_finalize(const float* __restrict__ uncap,
                                                  const float* __restrict__ writer_part,
                                                  const int* __restrict__ counts,
                                                  float* __restrict__ out)
{
    __shared__ float ru[256], rw[256];
    int t = threadIdx.x;
    float su = 0.f;
    for (int i = t; i < N_TOK; i += 256) su += uncap[i];
    float sw = writer_part[t];                    // exactly 256 partials
    ru[t] = su; rw[t] = sw;
    __syncthreads();
    for (int s = 128; s > 0; s >>= 1) {
        if (t < s) { ru[t] += ru[t + s]; rw[t] += rw[t + s]; }
        __syncthreads();
    }
    if (t == 0)
        out[(size_t)N_TOK * D_DIM] = ru[0] / (float)N_TOK
                                   + rw[0] / (float)(N_TOK * K_TOP * B_DIM);
    for (int i = t; i < M_EXP; i += 256)
        out[(size_t)N_TOK * D_DIM + 1 + i] = (float)counts[i];
}

extern "C" void kernel_launch(void* const* d_in, const int* in_sizes, int n_in,
                              void* d_out, int out_size, void* d_ws, size_t ws_size,
                              hipStream_t stream)
{
    const float* x = (const float*)d_in[0];
    const float* V = (const float*)d_in[1];
    const float* U = (const float*)d_in[2];
    float* out = (float*)d_out;

    float* ws     = (float*)d_ws;
    float* xn     = ws;                        // 2,097,152 f  (8.4 MB)
    float* P      = xn + 2097152;              // 16,777,216 f (67.1 MB): GEMM1 energy,
                                               //   then GEMM23 split-K partials (W fp32 + X fp16)
    float* uncap  = P + 16777216;              // 4096 f
    float* writer_part = uncap + 4096;         // 256 f (+pad)
    int*   topk_i = (int*)(writer_part + 512); // 65,536 i
    int*   counts = topk_i + 65536;            // 512 i (+pad)
    float* partV  = (float*)(counts + 1024);   // 65,536 f
    float* partU  = partV + 65536;             // 65,536 f
    unsigned short* hbf = (unsigned short*)(partU + 65536);  // 16,777,216 us (33.6 MB)
    unsigned short* U2t = hbf + 16777216;      // 2,097,152 us (4.2 MB)
    unsigned short* WXt = U2t + 2097152;       // 4,194,304 us (8.4 MB)
    unsigned short* R   = WXt + 4194304;       // 12,582,912 us (25.2 MB)
    unsigned short* Abf  = R;                  // 6,291,456 us (gemm1 A')
    unsigned short* Btbf = R + 6291456;        // 6,291,456 us (gemm1 B')
    unsigned short* writesb = R;               // 2,097,152 us (aliases Abf after GEMM1)
    float* energy = P;                         // 2,097,152 f ⊂ P (dead after topk2)
    float* Wp = P;                             // 4 x 4096 x 512 fp32 (33.6 MB) ⊂ P
    unsigned short* Xp = (unsigned short*)(P + 4 * 4096 * 512); // 4 x 4096 x 512 fp16 ⊂ P
    // total ws use ~148 MB

    k_norm_x_part<<<1536, 256, 0, stream>>>(x, xn, Abf, counts, V, U, partV, partU);
    k_norm_UV2  <<<512, 256, 0, stream>>>(V, U, partV, partU, Btbf, WXt, U2t);
    // GEMM1: h = A'(4096x1536) @ B'(1536x4096) -> hbf bf16 + energy fp32 (epilogue-fused)
    k_gemm8<KTOT, KTOT, 16, 1, 4096, 3><<<256, 512, 0, stream>>>(Abf, Btbf, energy, hbf);
    k_topk2     <<<N_TOK / 4, 256, 0, stream>>>(energy, hbf, topk_i, counts);
    // GEMM23: partial[ks] = hbf(4096x4096, K-slice ks) @ WXt^T -> W fp32 + X fp16 slabs
    k_gemm8<4096, 1024, 4, 4, 512, 5><<<256, 512, 0, stream>>>(hbf, WXt, Wp, Xp);
    // fused reduce + x_out + uncap + writes bf16
    k_reduce_fin<<<4096, 256, 0, stream>>>(Wp, Xp, xn, out, writesb, uncap);
    // GEMM4 fused writer-loss: hrecon tile vs hbf, per-block partials (no hrecon write)
    k_gemm8<D_DIM, D_DIM, 16, 1, 4096, 4><<<256, 512, 0, stream>>>(writesb, U2t, writer_part, hbf);
    k_finalize  <<<1, 256, 0, stream>>>(uncap, writer_part, counts, out);
}

// Round 14
// 210.073 us; speedup vs baseline: 1.0821x; 1.0030x over previous
//
#include <hip/hip_runtime.h>
#include <math.h>

#define N_TOK 4096
#define D_DIM 512
#define M_EXP 512
#define B_DIM 8
#define K_TOP 16
#define MB    4096          // M_EXP * B_DIM
#define UROW  4104          // (D_DIM+1) * B_DIM
#define EPSV  1e-8f
#define KTOT  1536          // 3 * D (split-bf16 K blocks for GEMM1)

typedef unsigned short ushort8 __attribute__((ext_vector_type(8)));
typedef unsigned short ushort4v __attribute__((ext_vector_type(4)));
typedef short short8 __attribute__((ext_vector_type(8)));
typedef float f32x4 __attribute__((ext_vector_type(4)));

__device__ inline float b2f(unsigned short u) {
    union { unsigned int i; float f; } c;
    c.i = ((unsigned int)u) << 16;
    return c.f;
}
__device__ inline unsigned short f2b(float f) {     // RNE bf16
    union { float f; unsigned int i; } c; c.f = f;
    unsigned int lsb = (c.i >> 16) & 1;
    c.i += 0x7fffu + lsb;
    return (unsigned short)(c.i >> 16);
}
__device__ inline unsigned short f2h(float f) {     // RNE fp16 via _Float16
    union { _Float16 h; unsigned short u; } c;
    c.h = (_Float16)f;
    return c.u;
}
__device__ inline float h2f(unsigned short u) {
    union { _Float16 h; unsigned short u; } c;
    c.u = u;
    return (float)c.h;
}
__device__ inline void gload_lds16(const unsigned short* g, unsigned short* l) {
    __builtin_amdgcn_global_load_lds(
        (const __attribute__((address_space(1))) unsigned int*)g,
        (__attribute__((address_space(3))) unsigned int*)l, 16, 0, 0);
}

// --- merged: blocks 0-1023 normalize x rows (+Abf); 1024-1535 V/U norm partials ---
__global__ __launch_bounds__(256) void k_norm_x_part(const float* __restrict__ x,
                                                     float* __restrict__ xn,
                                                     unsigned short* __restrict__ Abf,
                                                     int* __restrict__ counts,
                                                     const float* __restrict__ V,
                                                     const float* __restrict__ U,
                                                     float* __restrict__ partV,
                                                     float* __restrict__ partU)
{
    int blk = blockIdx.x;
    if (blk < 1024) {
        if (blk == 0) {
            counts[threadIdx.x] = 0;
            counts[threadIdx.x + 256] = 0;
        }
        int wave = threadIdx.x >> 6;
        int lane = threadIdx.x & 63;
        int n = blk * 4 + wave;
        const float4* xp = (const float4*)&x[(size_t)n * D_DIM + lane * 8];
        float4 a = xp[0], b = xp[1];
        float s = a.x*a.x + a.y*a.y + a.z*a.z + a.w*a.w
                + b.x*b.x + b.y*b.y + b.z*b.z + b.w*b.w;
        #pragma unroll
        for (int off = 1; off < 64; off <<= 1) s += __shfl_xor(s, off);
        float inv = 1.0f / fmaxf(sqrtf(s), EPSV);
        float v[8] = {a.x*inv, a.y*inv, a.z*inv, a.w*inv,
                      b.x*inv, b.y*inv, b.z*inv, b.w*inv};
        float4* op = (float4*)&xn[(size_t)n * D_DIM + lane * 8];
        op[0] = make_float4(v[0], v[1], v[2], v[3]);
        op[1] = make_float4(v[4], v[5], v[6], v[7]);
        ushort8 hi, lo;
        #pragma unroll
        for (int j = 0; j < 8; ++j) {
            unsigned short h = f2b(v[j]);
            hi[j] = h;
            lo[j] = f2b(v[j] - b2f(h));
        }
        size_t base = (size_t)n * KTOT + lane * 8;
        *(ushort8*)&Abf[base]        = hi;
        *(ushort8*)&Abf[base + 512]  = hi;
        *(ushort8*)&Abf[base + 1024] = lo;
    } else if (blk < 1280) {
        blk -= 1024;
        int s = blk >> 4;
        int t = (blk & 15) * 256 + threadIdx.x;
        float sum = 0.f;
        int d0 = s * 32;
        #pragma unroll 8
        for (int d = d0; d < d0 + 32; ++d) {
            float v = V[(size_t)d * MB + t];
            sum += v * v;
        }
        partV[(size_t)s * MB + t] = sum;
    } else {
        blk -= 1280;
        int s = blk >> 4;
        int t = (blk & 15) * 256 + threadIdx.x;
        int m = t >> 3, b = t & 7;
        size_t base = (size_t)m * UROW + b;
        int pbeg = s * 32;
        int pend = (s == 15) ? 513 : pbeg + 32;
        float sum = 0.f;
        for (int p = pbeg; p < pend; ++p) {
            float u = U[base + (size_t)p * 8];
            sum += u * u;
        }
        partU[(size_t)s * MB + t] = sum;
    }
}

// ---- merged normalize+emit: blocks 0-255 -> V path, 256-511 -> U path ----
__global__ __launch_bounds__(256) void k_norm_UV2(const float* __restrict__ V,
                                                  const float* __restrict__ U,
                                                  const float* __restrict__ partV,
                                                  const float* __restrict__ partU,
                                                  unsigned short* __restrict__ Btbf,
                                                  unsigned short* __restrict__ WXt,
                                                  unsigned short* __restrict__ U2t)
{
    int blk = blockIdx.x;
    if (blk < 256) {
        int s = blk >> 4;
        int t = (blk & 15) * 256 + threadIdx.x;
        float n2 = 0.f;
        #pragma unroll
        for (int i = 0; i < 16; ++i) n2 += partV[(size_t)i * MB + t];
        float inv = 1.0f / fmaxf(sqrtf(n2), EPSV);
        size_t row = (size_t)t * KTOT;
        int dbeg = s * 32;
        for (int d0 = dbeg; d0 < dbeg + 32; d0 += 8) {
            ushort8 hi, lo;
            #pragma unroll
            for (int j = 0; j < 8; ++j) {
                float f = V[(size_t)(d0 + j) * MB + t] * inv;
                unsigned short h = f2b(f);
                hi[j] = h;
                lo[j] = f2b(f - b2f(h));
                WXt[(size_t)(512 + d0 + j) * MB + t] = h;
            }
            *(ushort8*)&Btbf[row + d0]        = hi;
            *(ushort8*)&Btbf[row + 512 + d0]  = lo;
            *(ushort8*)&Btbf[row + 1024 + d0] = hi;
        }
    } else {
        blk -= 256;
        int s = blk >> 4;
        int t = (blk & 15) * 256 + threadIdx.x;
        int m = t >> 3, b = t & 7;
        size_t base = (size_t)m * UROW + b;
        float n2 = 0.f;
        #pragma unroll
        for (int i = 0; i < 16; ++i) n2 += partU[(size_t)i * MB + t];
        float inv = 1.0f / fmaxf(sqrtf(n2), EPSV);
        int pbeg = s * 32;
        for (int p0 = pbeg; p0 < pbeg + 32; p0 += 8) {
            ushort8 h8;
            #pragma unroll
            for (int j = 0; j < 8; ++j) {
                unsigned short h = f2b(U[base + (size_t)(p0 + j) * 8] * inv);
                h8[j] = h;
                WXt[(size_t)(p0 + j) * MB + t] = h;
            }
            *(ushort8*)&U2t[(size_t)t * D_DIM + p0] = h8;
        }
    }
}

// ================== 8-phase 256x256 bf16 GEMM (T3+T4+T5, k-slot swizzle) ==================
// A row-major (4096 x KROW), Bt col-major (Bt[col*KROW + k]).
// LDS: lds[buf][op][kc][row*32 + k], unit (buf,op,kc) = 16KB staged by 2 gload_lds16/thread.
// k-slot swizzle f(r)=(r>>1)&3: conflict-free ds_read_b128 (verified R9: conflicts -> 0).
// R14: STAGE ISSUED FIRST in each phase (T3 "key": loads enter flight before the
// ds_read+MFMA block, maximizing overlap distance to the vmcnt(4) drains at ph 4/8).
template<int KROW, int BUF, int KC, int MH, bool READB, int SBUF, int SOP, int SKC, bool DOVM>
__device__ __forceinline__ void gemm_phase(const unsigned short* __restrict__ A,
                                           const unsigned short* __restrict__ Bt,
                                           unsigned short (*lds)[2][2][8192],
                                           f32x4 (&acc)[8][4], short8 (&bfr)[4],
                                           int wr, int wc, int lane, int wid,
                                           int brow, int bcol, int stile)
{
    // ---- stage one unit FIRST (pre-swizzled global source, linear LDS dest) ----
    {
        const unsigned short* src = SOP ? Bt : A;
        int rbase = SOP ? bcol : brow;
        #pragma unroll
        for (int j = 0; j < 2; ++j) {
            int c = wid * 128 + j * 64 + lane;
            int row = c >> 2, k8 = c & 3;
            int k8s = k8 ^ ((row >> 1) & 3);
            const unsigned short* gp = src + (size_t)(rbase + row) * KROW
                                     + stile * 64 + SKC * 32 + k8s * 8;
            unsigned short* lp = lds[SBUF][SOP][SKC] + (wid * 128 + j * 64) * 8;
            gload_lds16(gp, lp);
        }
    }
    const unsigned short* aun = lds[BUF][0][KC];
    const unsigned short* bun = lds[BUF][1][KC];
    int ko = ((lane >> 4) ^ ((lane >> 1) & 3)) * 8;   // swizzled k-slot for this lane
    short8 af[4];
    #pragma unroll
    for (int mi = 0; mi < 4; ++mi) {
        int rowL = wr * 128 + (MH * 4 + mi) * 16 + (lane & 15);
        af[mi] = *(const short8*)&aun[rowL * 32 + ko];
    }
    if (READB) {
        #pragma unroll
        for (int ni = 0; ni < 4; ++ni) {
            int colL = wc * 64 + ni * 16 + (lane & 15);
            bfr[ni] = *(const short8*)&bun[colL * 32 + ko];
        }
    }
    __builtin_amdgcn_s_barrier();
    __builtin_amdgcn_s_setprio(1);
    #pragma unroll
    for (int mi = 0; mi < 4; ++mi)
        #pragma unroll
        for (int ni = 0; ni < 4; ++ni)
            acc[MH * 4 + mi][ni] = __builtin_amdgcn_mfma_f32_16x16x32_bf16(
                af[mi], bfr[ni], acc[MH * 4 + mi][ni], 0, 0, 0);
    __builtin_amdgcn_s_setprio(0);
    if (DOVM) asm volatile("s_waitcnt vmcnt(4)" ::: "memory");
    __builtin_amdgcn_s_barrier();
    __builtin_amdgcn_sched_barrier(0);   // phase boundary: next phase stays below
}

// KROW: row stride of A and Bt; KLEN: K extent per wg (split-K slice); NCOLT: output
// 256-col tiles; SPLITK: slices.
// OUTMODE 0: C fp32 (slabs of 4096*LDC).  2: Cb bf16.
// OUTMODE 3: Cb = h bf16 (ld 4096) + C = energy fp32 (ld 512).
// OUTMODE 4: writer-loss fused: Cb = hbf INPUT (masked h, ld 4096); C[bid] = block partial.
// OUTMODE 5: split partials: col<512 -> C fp32 slab (ld 512); col>=512 -> Cb fp16 slab (ld 512).
template<int KROW, int KLEN, int NCOLT, int SPLITK, int LDC, int OUTMODE>
__global__ __launch_bounds__(512, 1) void k_gemm8(const unsigned short* __restrict__ A,
                                                  const unsigned short* __restrict__ Bt,
                                                  float* __restrict__ C,
                                                  unsigned short* __restrict__ Cb)
{
    __shared__ unsigned short lds[2][2][2][8192];   // 128 KiB

    constexpr int KT   = KLEN / 64;
    constexpr int NIT  = KLEN / 128;
    constexpr int ROWT = 16;                        // 4096 / 256
    constexpr int NWG  = ROWT * NCOLT * SPLITK;     // must be % 8 == 0

    int tid = threadIdx.x;
    int wid = tid >> 6;
    int lane = tid & 63;
    int wr = wid >> 2, wc = wid & 3;

    int bid = blockIdx.x;
    int brow, bcol, ks;
    if constexpr (NCOLT == 16 && SPLITK == 1) {
        // L2-friendly 4x8 chunk per XCD: XCD x owns rows [(x&3)*4,+4) x cols [(x>>2)*8,+8)
        int x = bid & 7, p = bid >> 3;              // p in [0,32)
        brow = ((x & 3) * 4 + (p >> 3)) * 256;
        bcol = ((x >> 2) * 8 + (p & 7)) * 256;
        ks = 0;
    } else {
        int swz = (bid & 7) * (NWG / 8) + (bid >> 3);
        ks   = swz / (ROWT * NCOLT);
        int tile = swz % (ROWT * NCOLT);
        brow = (tile / NCOLT) * 256;
        bcol = (tile % NCOLT) * 256;
    }

    const unsigned short* Aofs = A + (size_t)ks * KLEN;
    const unsigned short* Bofs = Bt + (size_t)ks * KLEN;
    float* Cofs = C + (size_t)ks * 4096 * LDC;
    unsigned short* Xofs = (OUTMODE == 5) ? (Cb + (size_t)ks * 4096 * 512) : Cb;

    f32x4 acc[8][4] = {};
    short8 bfr[4];

    // ---- prologue: stage tile0 (4 units) + tile1.kc0 (2 units) ----
    auto stage0 = [&](int sbuf, int sop, int skc, int stile) {
        const unsigned short* src = sop ? Bofs : Aofs;
        int rbase = sop ? bcol : brow;
        #pragma unroll
        for (int j = 0; j < 2; ++j) {
            int c = wid * 128 + j * 64 + lane;
            int row = c >> 2, k8 = c & 3;
            int k8s = k8 ^ ((row >> 1) & 3);
            const unsigned short* gp = src + (size_t)(rbase + row) * KROW
                                     + stile * 64 + skc * 32 + k8s * 8;
            unsigned short* lp = lds[sbuf][sop][skc] + (wid * 128 + j * 64) * 8;
            gload_lds16(gp, lp);
        }
    };
    stage0(0, 0, 0, 0); stage0(0, 1, 0, 0);
    stage0(0, 0, 1, 0); stage0(0, 1, 1, 0);
    stage0(1, 0, 0, 1); stage0(1, 1, 0, 1);
    asm volatile("s_waitcnt vmcnt(4)" ::: "memory");   // drain tile0 kc0+kc1 (phases 1-4)
    __builtin_amdgcn_s_barrier();
    __builtin_amdgcn_sched_barrier(0);

    for (int i = 0; i < NIT; ++i) {
        int t1 = 2 * i + 1; if (t1 > KT - 1) t1 = KT - 1;
        int t2 = 2 * i + 2; if (t2 > KT - 1) t2 = KT - 1;
        int t3 = 2 * i + 3; if (t3 > KT - 1) t3 = KT - 1;
        gemm_phase<KROW, 0, 0, 0, true , 1, 0, 1, false>(Aofs, Bofs, lds, acc, bfr, wr, wc, lane, wid, brow, bcol, t1);
        gemm_phase<KROW, 0, 0, 1, false, 1, 1, 1, false>(Aofs, Bofs, lds, acc, bfr, wr, wc, lane, wid, brow, bcol, t1);
        gemm_phase<KROW, 0, 1, 0, true , 0, 0, 0, false>(Aofs, Bofs, lds, acc, bfr, wr, wc, lane, wid, brow, bcol, t2);
        gemm_phase<KROW, 0, 1, 1, false, 0, 1, 0, true >(Aofs, Bofs, lds, acc, bfr, wr, wc, lane, wid, brow, bcol, t2);
        gemm_phase<KROW, 1, 0, 0, true , 0, 0, 1, false>(Aofs, Bofs, lds, acc, bfr, wr, wc, lane, wid, brow, bcol, t2);
        gemm_phase<KROW, 1, 0, 1, false, 0, 1, 1, false>(Aofs, Bofs, lds, acc, bfr, wr, wc, lane, wid, brow, bcol, t2);
        gemm_phase<KROW, 1, 1, 0, true , 1, 0, 0, false>(Aofs, Bofs, lds, acc, bfr, wr, wc, lane, wid, brow, bcol, t3);
        gemm_phase<KROW, 1, 1, 1, false, 1, 1, 0, true >(Aofs, Bofs, lds, acc, bfr, wr, wc, lane, wid, brow, bcol, t3);
    }

    // epilogue: C/D layout col=lane&15, row=(lane>>4)*4+reg  [verified m89/m91]
    if (OUTMODE == 0 || OUTMODE == 2) {
        #pragma unroll
        for (int mr = 0; mr < 8; ++mr) {
            int row0 = brow + wr * 128 + mr * 16 + (lane >> 4) * 4;
            #pragma unroll
            for (int nr = 0; nr < 4; ++nr) {
                int col = bcol + wc * 64 + nr * 16 + (lane & 15);
                #pragma unroll
                for (int r = 0; r < 4; ++r) {
                    if (OUTMODE == 0)
                        Cofs[(size_t)(row0 + r) * LDC + col] = acc[mr][nr][r];
                    else
                        Cb[(size_t)(row0 + r) * LDC + col] = f2b(acc[mr][nr][r]);
                }
            }
        }
    } else if (OUTMODE == 5) {
        #pragma unroll
        for (int mr = 0; mr < 8; ++mr) {
            int row0 = brow + wr * 128 + mr * 16 + (lane >> 4) * 4;
            #pragma unroll
            for (int nr = 0; nr < 4; ++nr) {
                int col = bcol + wc * 64 + nr * 16 + (lane & 15);
                #pragma unroll
                for (int r = 0; r < 4; ++r) {
                    float v = acc[mr][nr][r];
                    if (col < 512)
                        Cofs[(size_t)(row0 + r) * 512 + col] = v;
                    else
                        Xofs[(size_t)(row0 + r) * 512 + (col - 512)] = f2h(v);
                }
            }
        }
    } else if (OUTMODE == 3) {
        #pragma unroll
        for (int mr = 0; mr < 8; ++mr) {
            int row0 = brow + wr * 128 + mr * 16 + (lane >> 4) * 4;
            #pragma unroll
            for (int nr = 0; nr < 4; ++nr) {
                int col = bcol + wc * 64 + nr * 16 + (lane & 15);
                f32x4 a = acc[mr][nr];
                #pragma unroll
                for (int r = 0; r < 4; ++r)
                    Cb[(size_t)(row0 + r) * 4096 + col] = f2b(a[r]);
                // energy: sum h^2 over the 8-lane b-group (3x shfl_xor tree)
                f32x4 sq;
                #pragma unroll
                for (int r = 0; r < 4; ++r) sq[r] = a[r] * a[r];
                #pragma unroll
                for (int off = 1; off <= 4; off <<= 1) {
                    sq[0] += __shfl_xor(sq[0], off);
                    sq[1] += __shfl_xor(sq[1], off);
                    sq[2] += __shfl_xor(sq[2], off);
                    sq[3] += __shfl_xor(sq[3], off);
                }
                if ((lane & 7) == 0) {
                    int e = ((bcol + wc * 64 + nr * 16) >> 3) + ((lane >> 3) & 1);
                    #pragma unroll
                    for (int r = 0; r < 4; ++r)
                        C[(size_t)(row0 + r) * 512 + e] = sq[r];
                }
            }
        }
    } else {  // OUTMODE 4: writer loss partial, no hrecon materialization
        float local = 0.f;
        #pragma unroll
        for (int mr = 0; mr < 8; ++mr) {
            int row0 = brow + wr * 128 + mr * 16 + (lane >> 4) * 4;
            #pragma unroll
            for (int nr = 0; nr < 4; ++nr) {
                int col = bcol + wc * 64 + nr * 16 + (lane & 15);
                #pragma unroll
                for (int r = 0; r < 4; ++r) {
                    unsigned short hbits = Cb[(size_t)(row0 + r) * 4096 + col];
                    if (hbits & 0x7fffu) {
                        float d = acc[mr][nr][r] - b2f(hbits);
                        local += d * d;
                    }
                }
            }
        }
        __syncthreads();                 // LDS dead after K-loop; reuse for reduction
        float* red = (float*)lds;
        red[tid] = local;
        __syncthreads();
        for (int s = 256; s > 0; s >>= 1) {
            if (tid < s) red[tid] += red[tid + s];
            __syncthreads();
        }
        if (tid == 0) C[bid] = red[0];
    }
}

// ---- top-16 from energy; mask hbf in place (one wave per token) ----
__global__ __launch_bounds__(256) void k_topk2(const float* __restrict__ energy,
                                               unsigned short* __restrict__ hbf,
                                               int* __restrict__ topk_idx,
                                               int* __restrict__ counts)
{
    int wave = threadIdx.x >> 6;
    int lane = threadIdx.x & 63;
    int n = blockIdx.x * 4 + wave;
    float ev[8];
    #pragma unroll
    for (int i = 0; i < 8; ++i) ev[i] = energy[(size_t)n * M_EXP + i * 64 + lane];
    for (int r = 0; r < K_TOP; ++r) {
        float bv = -1.0f; int bi = 0;
        #pragma unroll
        for (int i = 0; i < 8; ++i) {
            if (ev[i] > bv) { bv = ev[i]; bi = i * 64 + lane; }
        }
        #pragma unroll
        for (int off = 1; off < 64; off <<= 1) {
            float ov = __shfl_xor(bv, off);
            int   oi = __shfl_xor(bi, off);
            if (ov > bv || (ov == bv && oi < bi)) { bv = ov; bi = oi; }
        }
        if (lane == 0) {
            topk_idx[n * K_TOP + r] = bi;
            atomicAdd(&counts[bi], 1);
        }
        #pragma unroll
        for (int i = 0; i < 8; ++i)
            if (((bi >> 6) == i) && (lane == (bi & 63))) ev[i] = -INFINITY;
    }
    // zero non-selected experts' h (selected entries already hold h from GEMM1)
    ushort8 z = {0, 0, 0, 0, 0, 0, 0, 0};
    #pragma unroll
    for (int i = 0; i < 8; ++i) {
        int e = i * 64 + lane;
        if (ev[i] != -INFINITY)
            *(ushort8*)&hbf[(size_t)n * MB + e * 8] = z;
    }
}

// ---- fused: reduce 4 split-K partials (W fp32, X fp16) + x_out + uncap + writesb ----
__global__ __launch_bounds__(256) void k_reduce_fin(const float* __restrict__ Wp,
                                                    const unsigned short* __restrict__ Xp,
                                                    const float* __restrict__ xn,
                                                    float* __restrict__ x_out,
                                                    unsigned short* __restrict__ wb,
                                                    float* __restrict__ uncap)
{
    const size_t S = (size_t)4096 * 512;
    int n = blockIdx.x;
    int t = threadIdx.x;
    int c = t * 4;                               // 0..1023, step 4
    bool isW = (c < 512);
    int xc = isW ? c : (c - 512);
    float4 v;
    if (isW) {
        size_t base = (size_t)n * 512 + c;
        float4 a = *(const float4*)&Wp[base];
        float4 b = *(const float4*)&Wp[base + S];
        float4 cc = *(const float4*)&Wp[base + 2 * S];
        float4 d = *(const float4*)&Wp[base + 3 * S];
        v = make_float4(a.x + b.x + cc.x + d.x, a.y + b.y + cc.y + d.y,
                        a.z + b.z + cc.z + d.z, a.w + b.w + cc.w + d.w);
    } else {
        size_t base = (size_t)n * 512 + xc;
        ushort4v a = *(const ushort4v*)&Xp[base];
        ushort4v b = *(const ushort4v*)&Xp[base + S];
        ushort4v cc = *(const ushort4v*)&Xp[base + 2 * S];
        ushort4v d = *(const ushort4v*)&Xp[base + 3 * S];
        v = make_float4(h2f(a[0]) + h2f(b[0]) + h2f(cc[0]) + h2f(d[0]),
                        h2f(a[1]) + h2f(b[1]) + h2f(cc[1]) + h2f(d[1]),
                        h2f(a[2]) + h2f(b[2]) + h2f(cc[2]) + h2f(d[2]),
                        h2f(a[3]) + h2f(b[3]) + h2f(cc[3]) + h2f(d[3]));
    }
    float4 xv = *(const float4*)&xn[(size_t)n * D_DIM + xc];
    float4 yr;                                    // y (writes half) or resid (xhat half)
    if (isW) yr = make_float4(xv.x + v.x, xv.y + v.y, xv.z + v.z, xv.w + v.w);
    else     yr = make_float4(xv.x - v.x, xv.y - v.y, xv.z - v.z, xv.w - v.w);
    float local = yr.x*yr.x + yr.y*yr.y + yr.z*yr.z + yr.w*yr.w;

    __shared__ float red[256];
    __shared__ float sinv;
    red[t] = local;
    __syncthreads();
    for (int s = 64; s > 0; s >>= 1) {
        if ((t & 127) < s) red[t] += red[t + s];
        __syncthreads();
    }
    if (t == 0) {
        uncap[n] = red[128];                      // sum resid^2
        sinv = 1.0f / fmaxf(sqrtf(red[0]), EPSV); // from sum y^2
    }
    __syncthreads();
    if (isW) {
        float inv = sinv;
        *(float4*)&x_out[(size_t)n * D_DIM + c] =
            make_float4(yr.x*inv, yr.y*inv, yr.z*inv, yr.w*inv);
        ushort4v o;
        o[0] = f2b(yr.x); o[1] = f2b(yr.y); o[2] = f2b(yr.z); o[3] = f2b(yr.w);
        *(ushort4v*)&wb[(size_t)n * 512 + c] = o;
    }
}

// ---------------- final scalar reductions + counts ----------------
__global__ __launch_bounds__(256) void k_finalize(const float* __restrict__ uncap,
                                                  const float* __restrict__ writer_part,
                                                  const int* __restrict__ counts,
                                                  float* __restrict__ out)
{
    __shared__ float ru[256], rw[256];
    int t = threadIdx.x;
    float su = 0.f;
    for (int i = t; i < N_TOK; i += 256) su += uncap[i];
    float sw = writer_part[t];                    // exactly 256 partials
    ru[t] = su; rw[t] = sw;
    __syncthreads();
    for (int s = 128; s > 0; s >>= 1) {
        if (t < s) { ru[t] += ru[t + s]; rw[t] += rw[t + s]; }
        __syncthreads();
    }
    if (t == 0)
        out[(size_t)N_TOK * D_DIM] = ru[0] / (float)N_TOK
                                   + rw[0] / (float)(N_TOK * K_TOP * B_DIM);
    for (int i = t; i < M_EXP; i += 256)
        out[(size_t)N_TOK * D_DIM + 1 + i] = (float)counts[i];
}

extern "C" void kernel_launch(void* const* d_in, const int* in_sizes, int n_in,
                              void* d_out, int out_size, void* d_ws, size_t ws_size,
                              hipStream_t stream)
{
    const float* x = (const float*)d_in[0];
    const float* V = (const float*)d_in[1];
    const float* U = (const float*)d_in[2];
    float* out = (float*)d_out;

    float* ws     = (float*)d_ws;
    float* xn     = ws;                        // 2,097,152 f  (8.4 MB)
    float* P      = xn + 2097152;              // 16,777,216 f (67.1 MB): GEMM1 energy,
                                               //   then GEMM23 split-K partials (W fp32 + X fp16)
    float* uncap  = P + 16777216;              // 4096 f
    float* writer_part = uncap + 4096;         // 256 f (+pad)
    int*   topk_i = (int*)(writer_part + 512); // 65,536 i
    int*   counts = topk_i + 65536;            // 512 i (+pad)
    float* partV  = (float*)(counts + 1024);   // 65,536 f
    float* partU  = partV + 65536;             // 65,536 f
    unsigned short* hbf = (unsigned short*)(partU + 65536);  // 16,777,216 us (33.6 MB)
    unsigned short* U2t = hbf + 16777216;      // 2,097,152 us (4.2 MB)
    unsigned short* WXt = U2t + 2097152;       // 4,194,304 us (8.4 MB)
    unsigned short* R   = WXt + 4194304;       // 12,582,912 us (25.2 MB)
    unsigned short* Abf  = R;                  // 6,291,456 us (gemm1 A')
    unsigned short* Btbf = R + 6291456;        // 6,291,456 us (gemm1 B')
    unsigned short* writesb = R;               // 2,097,152 us (aliases Abf after GEMM1)
    float* energy = P;                         // 2,097,152 f ⊂ P (dead after topk2)
    float* Wp = P;                             // 4 x 4096 x 512 fp32 (33.6 MB) ⊂ P
    unsigned short* Xp = (unsigned short*)(P + 4 * 4096 * 512); // 4 x 4096 x 512 fp16 ⊂ P
    // total ws use ~148 MB

    k_norm_x_part<<<1536, 256, 0, stream>>>(x, xn, Abf, counts, V, U, partV, partU);
    k_norm_UV2  <<<512, 256, 0, stream>>>(V, U, partV, partU, Btbf, WXt, U2t);
    // GEMM1: h = A'(4096x1536) @ B'(1536x4096) -> hbf bf16 + energy fp32 (epilogue-fused)
    k_gemm8<KTOT, KTOT, 16, 1, 4096, 3><<<256, 512, 0, stream>>>(Abf, Btbf, energy, hbf);
    k_topk2     <<<N_TOK / 4, 256, 0, stream>>>(energy, hbf, topk_i, counts);
    // GEMM23: partial[ks] = hbf(4096x4096, K-slice ks) @ WXt^T -> W fp32 + X fp16 slabs
    k_gemm8<4096, 1024, 4, 4, 512, 5><<<256, 512, 0, stream>>>(hbf, WXt, Wp, Xp);
    // fused reduce + x_out + uncap + writes bf16
    k_reduce_fin<<<4096, 256, 0, stream>>>(Wp, Xp, xn, out, writesb, uncap);
    // GEMM4 fused writer-loss: hrecon tile vs hbf, per-block partials (no hrecon write)
    k_gemm8<D_DIM, D_DIM, 16, 1, 4096, 4><<<256, 512, 0, stream>>>(writesb, U2t, writer_part, hbf);
    k_finalize  <<<1, 256, 0, stream>>>(uncap, writer_part, counts, out);
}